// Round 1
// baseline (1798.094 us; speedup 1.0000x reference)
//
#include <hip/hip_runtime.h>
#include <hip/hip_bf16.h>
#include <math.h>

#define N_NODES 100000
#define N_EDGES 600000
#define F1 128   // conv1 width
#define F2 64    // conv2 width

// ---------------- degree / normalization ----------------

__global__ void deg_kernel(const int* __restrict__ dst, int* __restrict__ deg) {
    int e = blockIdx.x * blockDim.x + threadIdx.x;
    if (e < N_EDGES) atomicAdd(&deg[dst[e]], 1);
}

__global__ void dinv_kernel(const int* __restrict__ deg, float* __restrict__ dinv) {
    int n = blockIdx.x * blockDim.x + threadIdx.x;
    if (n < N_NODES) dinv[n] = rsqrtf((float)(deg[n] + 1));  // +1 self-loop
}

// ---------------- fp32 GEMM: out[N,HO] = X[N,K] @ W[K,HO] ----------------
// block = 256 threads, ROWS rows per block, each thread computes 8 cols of one row.

template<int K, int HO, int ROWS>
__global__ __launch_bounds__(256) void gemm_kernel(const float* __restrict__ X,
                                                   const float* __restrict__ W,
                                                   float* __restrict__ out) {
    constexpr int TPR = 256 / ROWS;   // threads per row
    constexpr int CPT = HO / TPR;     // cols per thread
    static_assert(CPT == 8, "layout assumes 8 cols/thread");
    __shared__ float Ws[K * HO];
    __shared__ float Xs[ROWS * K];
    const int tid = threadIdx.x;

    // stage W (row-major [K][HO])
    #pragma unroll
    for (int i = tid; i < K * HO / 4; i += 256)
        ((float4*)Ws)[i] = ((const float4*)W)[i];

    // stage X rows
    const int row0 = blockIdx.x * ROWS;
    for (int i = tid; i < ROWS * K / 4; i += 256) {
        int r = i / (K / 4);
        int row = row0 + r;
        ((float4*)Xs)[i] = (row < N_NODES)
            ? ((const float4*)X)[(size_t)row * (K / 4) + (i % (K / 4))]
            : make_float4(0.f, 0.f, 0.f, 0.f);
    }
    __syncthreads();

    const int r  = tid / TPR;
    const int c0 = (tid % TPR) * CPT;
    float4 acc0 = make_float4(0.f, 0.f, 0.f, 0.f);
    float4 acc1 = make_float4(0.f, 0.f, 0.f, 0.f);
    #pragma unroll 8
    for (int k = 0; k < K; k++) {
        const float xv = Xs[r * K + k];
        const float4 w0 = *(const float4*)&Ws[k * HO + c0];
        const float4 w1 = *(const float4*)&Ws[k * HO + c0 + 4];
        acc0.x += xv * w0.x; acc0.y += xv * w0.y; acc0.z += xv * w0.z; acc0.w += xv * w0.w;
        acc1.x += xv * w1.x; acc1.y += xv * w1.y; acc1.z += xv * w1.z; acc1.w += xv * w1.w;
    }
    const int row = row0 + r;
    if (row < N_NODES) {
        *(float4*)&out[(size_t)row * HO + c0]     = acc0;
        *(float4*)&out[(size_t)row * HO + c0 + 4] = acc1;
    }
}

// ---------------- h[n] = xw[n] * dinv[n]^2  (self-loop init) ----------------

template<int F>
__global__ void init_kernel(const float* __restrict__ xw, const float* __restrict__ dinv,
                            float* __restrict__ h) {
    const int C4 = F / 4;
    int i = blockIdx.x * blockDim.x + threadIdx.x;   // float4 index
    if (i >= N_NODES * C4) return;
    int n = i / C4;
    float d = dinv[n];
    float s = d * d;
    float4 v = ((const float4*)xw)[i];
    v.x *= s; v.y *= s; v.z *= s; v.w *= s;
    ((float4*)h)[i] = v;
}

// ---------------- edge scatter: h[dst] += xw[src] * dinv[src]*dinv[dst] ----------------

template<int F>
__global__ void scatter_kernel(const int* __restrict__ src, const int* __restrict__ dst,
                               const float* __restrict__ dinv,
                               const float* __restrict__ xw, float* __restrict__ h) {
    const int C4 = F / 4;
    int i = blockIdx.x * blockDim.x + threadIdx.x;   // (edge, float4-chunk)
    if (i >= N_EDGES * C4) return;
    int e = i / C4;
    int c = i % C4;
    int s = src[e], d = dst[e];
    float norm = dinv[s] * dinv[d];
    float4 v = ((const float4*)xw)[(size_t)s * C4 + c];
    float* hp = &h[(size_t)d * F + c * 4];
    atomicAdd(hp + 0, v.x * norm);
    atomicAdd(hp + 1, v.y * norm);
    atomicAdd(hp + 2, v.z * norm);
    atomicAdd(hp + 3, v.w * norm);
}

// ---------------- h = relu(h + b) ----------------

template<int F>
__global__ void bias_relu_kernel(float* __restrict__ h, const float* __restrict__ b) {
    const int C4 = F / 4;
    int i = blockIdx.x * blockDim.x + threadIdx.x;   // float4 index
    if (i >= N_NODES * C4) return;
    int c = (i % C4) * 4;
    float4 bv = *(const float4*)&b[c];
    float4 v = ((float4*)h)[i];
    v.x = fmaxf(v.x + bv.x, 0.f);
    v.y = fmaxf(v.y + bv.y, 0.f);
    v.z = fmaxf(v.z + bv.z, 0.f);
    v.w = fmaxf(v.w + bv.w, 0.f);
    ((float4*)h)[i] = v;
}

// ---------------- head: gelu(h2 @ Wh1 + bh1) @ Wh2 + bh2 -> sigmoid ----------------
// 16 threads per node; 16 nodes per 256-thread block.

__global__ __launch_bounds__(256) void head_kernel(const float* __restrict__ h2,
                                                   const float* __restrict__ Wh1,
                                                   const float* __restrict__ bh1,
                                                   const float* __restrict__ Wh2,
                                                   const float* __restrict__ bh2,
                                                   float* __restrict__ out) {
    __shared__ float W1s[64 * 16];
    __shared__ float h2s[16 * 64];
    __shared__ float W2s[16];
    __shared__ float b1s[16];
    const int tid = threadIdx.x;
    const int node0 = blockIdx.x * 16;

    ((float4*)W1s)[tid] = ((const float4*)Wh1)[tid];   // 1024 floats = 256 float4
    if (tid < 16) { W2s[tid] = Wh2[tid]; b1s[tid] = bh1[tid]; }
    {
        int node = node0 + tid / 16;
        ((float4*)h2s)[tid] = (node < N_NODES)
            ? ((const float4*)h2)[(size_t)node * 16 + (tid % 16)]
            : make_float4(0.f, 0.f, 0.f, 0.f);
    }
    __syncthreads();

    const int l  = tid & 15;
    const int nl = tid >> 4;
    const int node = node0 + nl;

    float s = b1s[l];
    #pragma unroll 8
    for (int k = 0; k < 64; k++)
        s += h2s[nl * 64 + k] * W1s[k * 16 + l];
    // exact GELU
    float g = 0.5f * s * (1.f + erff(s * 0.70710678118654752f));
    float p = g * W2s[l];
    p += __shfl_xor(p, 1);
    p += __shfl_xor(p, 2);
    p += __shfl_xor(p, 4);
    p += __shfl_xor(p, 8);
    if (l == 0 && node < N_NODES) {
        float z = p + bh2[0];
        out[node] = 1.f / (1.f + expf(-z));
    }
}

// ---------------- launch ----------------

extern "C" void kernel_launch(void* const* d_in, const int* in_sizes, int n_in,
                              void* d_out, int out_size, void* d_ws, size_t ws_size,
                              hipStream_t stream) {
    const float* x   = (const float*)d_in[0];
    const int*   ei  = (const int*)d_in[1];
    const float* W1  = (const float*)d_in[2];
    const float* b1  = (const float*)d_in[3];
    const float* W2  = (const float*)d_in[4];
    const float* b2  = (const float*)d_in[5];
    const float* Wh1 = (const float*)d_in[6];
    const float* bh1 = (const float*)d_in[7];
    const float* Wh2 = (const float*)d_in[8];
    const float* bh2 = (const float*)d_in[9];
    float* out = (float*)d_out;

    const int* srcA = ei;             // edge_index[0]
    const int* dstA = ei + N_EDGES;   // edge_index[1]

    char* ws = (char*)d_ws;
    float* dinv = (float*)ws;                                   // N floats
    int*   deg  = (int*)(ws + (512u * 1024u));                  // N ints
    const size_t szNF = (size_t)N_NODES * F1 * sizeof(float);   // 51.2 MB
    float* bufA = (float*)(ws + (1u << 20));                    // xw1, later xw2|h2
    float* bufB = (float*)(ws + (1u << 20) + szNF);             // h1
    float* xw2  = bufA;                                         // N x 64
    float* h2   = bufA + (size_t)N_NODES * F2;                  // N x 64

    // degree + dinv
    hipMemsetAsync(deg, 0, N_NODES * sizeof(int), stream);
    deg_kernel<<<(N_EDGES + 255) / 256, 256, 0, stream>>>(dstA, deg);
    dinv_kernel<<<(N_NODES + 255) / 256, 256, 0, stream>>>(deg, dinv);

    // layer 1: xw1 = x @ W1; agg; +b1, relu
    gemm_kernel<128, 128, 16><<<(N_NODES + 15) / 16, 256, 0, stream>>>(x, W1, bufA);
    init_kernel<128><<<(N_NODES * 32 + 255) / 256, 256, 0, stream>>>(bufA, dinv, bufB);
    scatter_kernel<128><<<(N_EDGES * 32 + 255) / 256, 256, 0, stream>>>(srcA, dstA, dinv, bufA, bufB);
    bias_relu_kernel<128><<<(N_NODES * 32 + 255) / 256, 256, 0, stream>>>(bufB, b1);

    // layer 2: xw2 = h1 @ W2; agg; +b2, relu
    gemm_kernel<128, 64, 32><<<(N_NODES + 31) / 32, 256, 0, stream>>>(bufB, W2, xw2);
    init_kernel<64><<<(N_NODES * 16 + 255) / 256, 256, 0, stream>>>(xw2, dinv, h2);
    scatter_kernel<64><<<(N_EDGES * 16 + 255) / 256, 256, 0, stream>>>(srcA, dstA, dinv, xw2, h2);
    bias_relu_kernel<64><<<(N_NODES * 16 + 255) / 256, 256, 0, stream>>>(h2, b2);

    // head
    head_kernel<<<(N_NODES + 15) / 16, 256, 0, stream>>>(h2, Wh1, bh1, Wh2, bh2, out);
}

// Round 2
// 540.044 us; speedup vs baseline: 3.3295x; 3.3295x over previous
//
#include <hip/hip_runtime.h>
#include <hip/hip_bf16.h>
#include <math.h>

#define N_NODES 100000
#define N_EDGES 600000
#define F1 128   // conv1 width
#define F2 64    // conv2 width

// ---------------- degree / normalization ----------------

__global__ void deg_kernel(const int* __restrict__ dst, int* __restrict__ deg) {
    int e = blockIdx.x * blockDim.x + threadIdx.x;
    if (e < N_EDGES) atomicAdd(&deg[dst[e]], 1);
}

__global__ void dinv_kernel(const int* __restrict__ deg, float* __restrict__ dinv) {
    int n = blockIdx.x * blockDim.x + threadIdx.x;
    if (n < N_NODES) dinv[n] = rsqrtf((float)(deg[n] + 1));  // +1 self-loop
}

// ---------------- exclusive scan of deg -> off (single block) ----------------

__global__ __launch_bounds__(1024) void scan_kernel(const int* __restrict__ deg,
                                                    int* __restrict__ off) {
    __shared__ int sums[1024];
    const int tid = threadIdx.x;
    const int per = (N_NODES + 1023) / 1024;   // 98
    const int base = tid * per;
    int s = 0;
    for (int i = 0; i < per; i++) {
        int idx = base + i;
        if (idx < N_NODES) s += deg[idx];
    }
    sums[tid] = s;
    __syncthreads();
    // Hillis-Steele inclusive scan
    for (int d = 1; d < 1024; d <<= 1) {
        int v = (tid >= d) ? sums[tid - d] : 0;
        __syncthreads();
        sums[tid] += v;
        __syncthreads();
    }
    int run = (tid > 0) ? sums[tid - 1] : 0;
    for (int i = 0; i < per; i++) {
        int idx = base + i;
        if (idx < N_NODES) {
            int v = deg[idx];
            off[idx] = run;
            run += v;
        }
    }
    if (tid == 1023) off[N_NODES] = run;
}

__global__ void copy_kernel(const int* __restrict__ a, int* __restrict__ b, int n) {
    int i = blockIdx.x * blockDim.x + threadIdx.x;
    if (i < n) b[i] = a[i];
}

// ---------------- CSR fill: bucket edges by dst ----------------

__global__ void fill_kernel(const int* __restrict__ src, const int* __restrict__ dst,
                            int* __restrict__ cur, int* __restrict__ csr_src) {
    int e = blockIdx.x * blockDim.x + threadIdx.x;
    if (e < N_EDGES) {
        int d = dst[e];
        int pos = atomicAdd(&cur[d], 1);
        csr_src[pos] = src[e];
    }
}

// ---------------- fp32 GEMM: out[N,HO] = X[N,K] @ W[K,HO] ----------------

template<int K, int HO, int ROWS>
__global__ __launch_bounds__(256) void gemm_kernel(const float* __restrict__ X,
                                                   const float* __restrict__ W,
                                                   float* __restrict__ out) {
    constexpr int TPR = 256 / ROWS;   // threads per row
    constexpr int CPT = HO / TPR;     // cols per thread
    static_assert(CPT == 8, "layout assumes 8 cols/thread");
    __shared__ float Ws[K * HO];
    __shared__ float Xs[ROWS * K];
    const int tid = threadIdx.x;

    #pragma unroll
    for (int i = tid; i < K * HO / 4; i += 256)
        ((float4*)Ws)[i] = ((const float4*)W)[i];

    const int row0 = blockIdx.x * ROWS;
    for (int i = tid; i < ROWS * K / 4; i += 256) {
        int r = i / (K / 4);
        int row = row0 + r;
        ((float4*)Xs)[i] = (row < N_NODES)
            ? ((const float4*)X)[(size_t)row * (K / 4) + (i % (K / 4))]
            : make_float4(0.f, 0.f, 0.f, 0.f);
    }
    __syncthreads();

    const int r  = tid / TPR;
    const int c0 = (tid % TPR) * CPT;
    float4 acc0 = make_float4(0.f, 0.f, 0.f, 0.f);
    float4 acc1 = make_float4(0.f, 0.f, 0.f, 0.f);
    #pragma unroll 8
    for (int k = 0; k < K; k++) {
        const float xv = Xs[r * K + k];
        const float4 w0 = *(const float4*)&Ws[k * HO + c0];
        const float4 w1 = *(const float4*)&Ws[k * HO + c0 + 4];
        acc0.x += xv * w0.x; acc0.y += xv * w0.y; acc0.z += xv * w0.z; acc0.w += xv * w0.w;
        acc1.x += xv * w1.x; acc1.y += xv * w1.y; acc1.z += xv * w1.z; acc1.w += xv * w1.w;
    }
    const int row = row0 + r;
    if (row < N_NODES) {
        *(float4*)&out[(size_t)row * HO + c0]     = acc0;
        *(float4*)&out[(size_t)row * HO + c0 + 4] = acc1;
    }
}

// ---------------- fused aggregation: h[n] = relu(sum_{s in N(n)} xw[s]*norm + xw[n]*dinv^2 + b) ----------------

template<int F>
__global__ __launch_bounds__(256) void gather_kernel(const float* __restrict__ xw,
                                                     const float* __restrict__ dinv,
                                                     const int* __restrict__ off,
                                                     const int* __restrict__ csr_src,
                                                     const float* __restrict__ bias,
                                                     float* __restrict__ h) {
    constexpr int LANES = F / 4;        // float4 lanes per node: 32 or 16
    constexpr int NPB = 256 / LANES;    // nodes per block
    const int n = blockIdx.x * NPB + threadIdx.x / LANES;
    if (n >= N_NODES) return;
    const int c = threadIdx.x % LANES;

    const float dn = dinv[n];
    float4 acc = ((const float4*)xw)[(size_t)n * LANES + c];
    const float sl = dn * dn;           // self-loop norm
    acc.x *= sl; acc.y *= sl; acc.z *= sl; acc.w *= sl;

    const int e1 = off[n + 1];
    for (int j = off[n]; j < e1; j++) {
        const int s = csr_src[j];
        const float nr = dinv[s] * dn;
        const float4 v = ((const float4*)xw)[(size_t)s * LANES + c];
        acc.x += v.x * nr; acc.y += v.y * nr; acc.z += v.z * nr; acc.w += v.w * nr;
    }
    const float4 bv = *(const float4*)&bias[c * 4];
    acc.x = fmaxf(acc.x + bv.x, 0.f);
    acc.y = fmaxf(acc.y + bv.y, 0.f);
    acc.z = fmaxf(acc.z + bv.z, 0.f);
    acc.w = fmaxf(acc.w + bv.w, 0.f);
    ((float4*)h)[(size_t)n * LANES + c] = acc;
}

// ---------------- head: gelu(h2 @ Wh1 + bh1) @ Wh2 + bh2 -> sigmoid ----------------

__global__ __launch_bounds__(256) void head_kernel(const float* __restrict__ h2,
                                                   const float* __restrict__ Wh1,
                                                   const float* __restrict__ bh1,
                                                   const float* __restrict__ Wh2,
                                                   const float* __restrict__ bh2,
                                                   float* __restrict__ out) {
    __shared__ float W1s[64 * 16];
    __shared__ float h2s[16 * 64];
    __shared__ float W2s[16];
    __shared__ float b1s[16];
    const int tid = threadIdx.x;
    const int node0 = blockIdx.x * 16;

    ((float4*)W1s)[tid] = ((const float4*)Wh1)[tid];
    if (tid < 16) { W2s[tid] = Wh2[tid]; b1s[tid] = bh1[tid]; }
    {
        int node = node0 + tid / 16;
        ((float4*)h2s)[tid] = (node < N_NODES)
            ? ((const float4*)h2)[(size_t)node * 16 + (tid % 16)]
            : make_float4(0.f, 0.f, 0.f, 0.f);
    }
    __syncthreads();

    const int l  = tid & 15;
    const int nl = tid >> 4;
    const int node = node0 + nl;

    float s = b1s[l];
    #pragma unroll 8
    for (int k = 0; k < 64; k++)
        s += h2s[nl * 64 + k] * W1s[k * 16 + l];
    float g = 0.5f * s * (1.f + erff(s * 0.70710678118654752f));
    float p = g * W2s[l];
    p += __shfl_xor(p, 1);
    p += __shfl_xor(p, 2);
    p += __shfl_xor(p, 4);
    p += __shfl_xor(p, 8);
    if (l == 0 && node < N_NODES) {
        float z = p + bh2[0];
        out[node] = 1.f / (1.f + expf(-z));
    }
}

// ---------------- launch ----------------

extern "C" void kernel_launch(void* const* d_in, const int* in_sizes, int n_in,
                              void* d_out, int out_size, void* d_ws, size_t ws_size,
                              hipStream_t stream) {
    const float* x   = (const float*)d_in[0];
    const int*   ei  = (const int*)d_in[1];
    const float* W1  = (const float*)d_in[2];
    const float* b1  = (const float*)d_in[3];
    const float* W2  = (const float*)d_in[4];
    const float* b2  = (const float*)d_in[5];
    const float* Wh1 = (const float*)d_in[6];
    const float* bh1 = (const float*)d_in[7];
    const float* Wh2 = (const float*)d_in[8];
    const float* bh2 = (const float*)d_in[9];
    float* out = (float*)d_out;

    const int* srcA = ei;             // edge_index[0]
    const int* dstA = ei + N_EDGES;   // edge_index[1]

    char* ws = (char*)d_ws;
    const size_t MB = 1u << 20;
    float* dinv    = (float*)(ws);                    // N f32
    int*   deg     = (int*)  (ws + MB / 2);           // N i32
    int*   off     = (int*)  (ws + MB);               // N+1 i32
    int*   cur     = (int*)  (ws + MB + MB / 2);      // N i32
    int*   csr_src = (int*)  (ws + 2 * MB);           // E i32 (2.4MB)
    const size_t szNF = (size_t)N_NODES * F1 * sizeof(float);   // 51.2 MB
    float* bufA = (float*)(ws + 5 * MB);              // xw1; later xw2|h2
    float* bufB = (float*)(ws + 5 * MB + szNF);       // h1
    float* xw2  = bufA;                               // N x 64
    float* h2   = bufA + (size_t)N_NODES * F2;        // N x 64

    // degree + dinv + CSR
    hipMemsetAsync(deg, 0, N_NODES * sizeof(int), stream);
    deg_kernel<<<(N_EDGES + 255) / 256, 256, 0, stream>>>(dstA, deg);
    dinv_kernel<<<(N_NODES + 255) / 256, 256, 0, stream>>>(deg, dinv);
    scan_kernel<<<1, 1024, 0, stream>>>(deg, off);
    copy_kernel<<<(N_NODES + 255) / 256, 256, 0, stream>>>(off, cur, N_NODES);
    fill_kernel<<<(N_EDGES + 255) / 256, 256, 0, stream>>>(srcA, dstA, cur, csr_src);

    // layer 1
    gemm_kernel<128, 128, 16><<<(N_NODES + 15) / 16, 256, 0, stream>>>(x, W1, bufA);
    gather_kernel<128><<<(N_NODES * 32 + 255) / 256, 256, 0, stream>>>(bufA, dinv, off, csr_src, b1, bufB);

    // layer 2
    gemm_kernel<128, 64, 32><<<(N_NODES + 31) / 32, 256, 0, stream>>>(bufB, W2, xw2);
    gather_kernel<64><<<(N_NODES * 16 + 255) / 256, 256, 0, stream>>>(xw2, dinv, off, csr_src, b2, h2);

    // head
    head_kernel<<<(N_NODES + 15) / 16, 256, 0, stream>>>(h2, Wh1, bh1, Wh2, bh2, out);
}

// Round 3
// 372.519 us; speedup vs baseline: 4.8268x; 1.4497x over previous
//
#include <hip/hip_runtime.h>
#include <hip/hip_bf16.h>
#include <math.h>

#define N_NODES 100000
#define N_EDGES 600000
#define F1 128   // conv1 width
#define F2 64    // conv2 width

// ---------------- degree / normalization ----------------

__global__ void deg_kernel(const int* __restrict__ dst, int* __restrict__ deg) {
    int e = blockIdx.x * blockDim.x + threadIdx.x;
    if (e < N_EDGES) atomicAdd(&deg[dst[e]], 1);
}

__global__ void dinv_kernel(const int* __restrict__ deg, float* __restrict__ dinv) {
    int n = blockIdx.x * blockDim.x + threadIdx.x;
    if (n < N_NODES) dinv[n] = rsqrtf((float)(deg[n] + 1));  // +1 self-loop
}

// ---------------- region allocation: off[n] = base for node n's bucket ----------------
// Wave-level inclusive scan + one atomicAdd per wave. Region order across waves is
// arbitrary; each node still gets a contiguous region of size deg[n].

__global__ void alloc_kernel(const int* __restrict__ deg, int* __restrict__ counter,
                             int* __restrict__ off) {
    int i = blockIdx.x * blockDim.x + threadIdx.x;
    int d = (i < N_NODES) ? deg[i] : 0;
    int incl = d;
    #pragma unroll
    for (int o = 1; o < 64; o <<= 1) {
        int v = __shfl_up(incl, o);
        if ((threadIdx.x & 63) >= o) incl += v;
    }
    int base = 0;
    if ((threadIdx.x & 63) == 63) base = atomicAdd(counter, incl);  // lane63 incl = wave total
    base = __shfl(base, 63);
    if (i < N_NODES) off[i] = base + incl - d;
}

__global__ void copy_kernel(const int* __restrict__ a, int* __restrict__ b, int n) {
    int i = blockIdx.x * blockDim.x + threadIdx.x;
    if (i < n) b[i] = a[i];
}

// ---------------- CSR fill: bucket edges by dst ----------------

__global__ void fill_kernel(const int* __restrict__ src, const int* __restrict__ dst,
                            int* __restrict__ cur, int* __restrict__ csr_src) {
    int e = blockIdx.x * blockDim.x + threadIdx.x;
    if (e < N_EDGES) {
        int d = dst[e];
        int pos = atomicAdd(&cur[d], 1);
        csr_src[pos] = src[e];
    }
}

// ---------------- fp32 GEMM: out[N,HO] = X[N,K] @ W[K,HO] ----------------

template<int K, int HO, int ROWS>
__global__ __launch_bounds__(256) void gemm_kernel(const float* __restrict__ X,
                                                   const float* __restrict__ W,
                                                   float* __restrict__ out) {
    constexpr int TPR = 256 / ROWS;   // threads per row
    constexpr int CPT = HO / TPR;     // cols per thread
    static_assert(CPT == 8, "layout assumes 8 cols/thread");
    __shared__ float Ws[K * HO];
    __shared__ float Xs[ROWS * K];
    const int tid = threadIdx.x;

    #pragma unroll
    for (int i = tid; i < K * HO / 4; i += 256)
        ((float4*)Ws)[i] = ((const float4*)W)[i];

    const int row0 = blockIdx.x * ROWS;
    for (int i = tid; i < ROWS * K / 4; i += 256) {
        int r = i / (K / 4);
        int row = row0 + r;
        ((float4*)Xs)[i] = (row < N_NODES)
            ? ((const float4*)X)[(size_t)row * (K / 4) + (i % (K / 4))]
            : make_float4(0.f, 0.f, 0.f, 0.f);
    }
    __syncthreads();

    const int r  = tid / TPR;
    const int c0 = (tid % TPR) * CPT;
    float4 acc0 = make_float4(0.f, 0.f, 0.f, 0.f);
    float4 acc1 = make_float4(0.f, 0.f, 0.f, 0.f);
    #pragma unroll 8
    for (int k = 0; k < K; k++) {
        const float xv = Xs[r * K + k];
        const float4 w0 = *(const float4*)&Ws[k * HO + c0];
        const float4 w1 = *(const float4*)&Ws[k * HO + c0 + 4];
        acc0.x += xv * w0.x; acc0.y += xv * w0.y; acc0.z += xv * w0.z; acc0.w += xv * w0.w;
        acc1.x += xv * w1.x; acc1.y += xv * w1.y; acc1.z += xv * w1.z; acc1.w += xv * w1.w;
    }
    const int row = row0 + r;
    if (row < N_NODES) {
        *(float4*)&out[(size_t)row * HO + c0]     = acc0;
        *(float4*)&out[(size_t)row * HO + c0 + 4] = acc1;
    }
}

// ---------------- fused aggregation: h[n] = relu(sum_{s in N(n)} xw[s]*norm + xw[n]*dinv^2 + b) ----------------

template<int F>
__global__ __launch_bounds__(256) void gather_kernel(const float* __restrict__ xw,
                                                     const float* __restrict__ dinv,
                                                     const int* __restrict__ off,
                                                     const int* __restrict__ deg,
                                                     const int* __restrict__ csr_src,
                                                     const float* __restrict__ bias,
                                                     float* __restrict__ h) {
    constexpr int LANES = F / 4;        // float4 lanes per node: 32 or 16
    constexpr int NPB = 256 / LANES;    // nodes per block
    const int n = blockIdx.x * NPB + threadIdx.x / LANES;
    if (n >= N_NODES) return;
    const int c = threadIdx.x % LANES;

    const float dn = dinv[n];
    float4 acc = ((const float4*)xw)[(size_t)n * LANES + c];
    const float sl = dn * dn;           // self-loop norm
    acc.x *= sl; acc.y *= sl; acc.z *= sl; acc.w *= sl;

    const int e0 = off[n];
    const int e1 = e0 + deg[n];
    for (int j = e0; j < e1; j++) {
        const int s = csr_src[j];
        const float nr = dinv[s] * dn;
        const float4 v = ((const float4*)xw)[(size_t)s * LANES + c];
        acc.x += v.x * nr; acc.y += v.y * nr; acc.z += v.z * nr; acc.w += v.w * nr;
    }
    const float4 bv = *(const float4*)&bias[c * 4];
    acc.x = fmaxf(acc.x + bv.x, 0.f);
    acc.y = fmaxf(acc.y + bv.y, 0.f);
    acc.z = fmaxf(acc.z + bv.z, 0.f);
    acc.w = fmaxf(acc.w + bv.w, 0.f);
    ((float4*)h)[(size_t)n * LANES + c] = acc;
}

// ---------------- head: gelu(h2 @ Wh1 + bh1) @ Wh2 + bh2 -> sigmoid ----------------

__global__ __launch_bounds__(256) void head_kernel(const float* __restrict__ h2,
                                                   const float* __restrict__ Wh1,
                                                   const float* __restrict__ bh1,
                                                   const float* __restrict__ Wh2,
                                                   const float* __restrict__ bh2,
                                                   float* __restrict__ out) {
    __shared__ float W1s[64 * 16];
    __shared__ float h2s[16 * 64];
    __shared__ float W2s[16];
    __shared__ float b1s[16];
    const int tid = threadIdx.x;
    const int node0 = blockIdx.x * 16;

    ((float4*)W1s)[tid] = ((const float4*)Wh1)[tid];
    if (tid < 16) { W2s[tid] = Wh2[tid]; b1s[tid] = bh1[tid]; }
    {
        int node = node0 + tid / 16;
        ((float4*)h2s)[tid] = (node < N_NODES)
            ? ((const float4*)h2)[(size_t)node * 16 + (tid % 16)]
            : make_float4(0.f, 0.f, 0.f, 0.f);
    }
    __syncthreads();

    const int l  = tid & 15;
    const int nl = tid >> 4;
    const int node = node0 + nl;

    float s = b1s[l];
    #pragma unroll 8
    for (int k = 0; k < 64; k++)
        s += h2s[nl * 64 + k] * W1s[k * 16 + l];
    float g = 0.5f * s * (1.f + erff(s * 0.70710678118654752f));
    float p = g * W2s[l];
    p += __shfl_xor(p, 1);
    p += __shfl_xor(p, 2);
    p += __shfl_xor(p, 4);
    p += __shfl_xor(p, 8);
    if (l == 0 && node < N_NODES) {
        float z = p + bh2[0];
        out[node] = 1.f / (1.f + expf(-z));
    }
}

// ---------------- launch ----------------

extern "C" void kernel_launch(void* const* d_in, const int* in_sizes, int n_in,
                              void* d_out, int out_size, void* d_ws, size_t ws_size,
                              hipStream_t stream) {
    const float* x   = (const float*)d_in[0];
    const int*   ei  = (const int*)d_in[1];
    const float* W1  = (const float*)d_in[2];
    const float* b1  = (const float*)d_in[3];
    const float* W2  = (const float*)d_in[4];
    const float* b2  = (const float*)d_in[5];
    const float* Wh1 = (const float*)d_in[6];
    const float* bh1 = (const float*)d_in[7];
    const float* Wh2 = (const float*)d_in[8];
    const float* bh2 = (const float*)d_in[9];
    float* out = (float*)d_out;

    const int* srcA = ei;             // edge_index[0]
    const int* dstA = ei + N_EDGES;   // edge_index[1]

    char* ws = (char*)d_ws;
    const size_t MB = 1u << 20;
    float* dinv    = (float*)(ws);                    // N f32
    int*   deg     = (int*)  (ws + MB / 2);           // N i32 (+1 counter)
    int*   counter = deg + N_NODES;                   // 1 i32
    int*   off     = (int*)  (ws + MB);               // N i32
    int*   cur     = (int*)  (ws + MB + MB / 2);      // N i32
    int*   csr_src = (int*)  (ws + 2 * MB);           // E i32 (2.4MB)
    const size_t szNF = (size_t)N_NODES * F1 * sizeof(float);   // 51.2 MB
    float* bufA = (float*)(ws + 5 * MB);              // xw1; later xw2|h2
    float* bufB = (float*)(ws + 5 * MB + szNF);       // h1
    float* xw2  = bufA;                               // N x 64
    float* h2   = bufA + (size_t)N_NODES * F2;        // N x 64

    // degree + dinv + bucket allocation + CSR fill
    hipMemsetAsync(deg, 0, (N_NODES + 1) * sizeof(int), stream);   // deg + counter
    deg_kernel<<<(N_EDGES + 255) / 256, 256, 0, stream>>>(dstA, deg);
    dinv_kernel<<<(N_NODES + 255) / 256, 256, 0, stream>>>(deg, dinv);
    alloc_kernel<<<(N_NODES + 255) / 256, 256, 0, stream>>>(deg, counter, off);
    copy_kernel<<<(N_NODES + 255) / 256, 256, 0, stream>>>(off, cur, N_NODES);
    fill_kernel<<<(N_EDGES + 255) / 256, 256, 0, stream>>>(srcA, dstA, cur, csr_src);

    // layer 1
    gemm_kernel<128, 128, 16><<<(N_NODES + 15) / 16, 256, 0, stream>>>(x, W1, bufA);
    gather_kernel<128><<<(N_NODES * 32 + 255) / 256, 256, 0, stream>>>(bufA, dinv, off, deg, csr_src, b1, bufB);

    // layer 2
    gemm_kernel<128, 64, 32><<<(N_NODES + 31) / 32, 256, 0, stream>>>(bufB, W2, xw2);
    gather_kernel<64><<<(N_NODES * 16 + 255) / 256, 256, 0, stream>>>(xw2, dinv, off, deg, csr_src, b2, h2);

    // head
    head_kernel<<<(N_NODES + 15) / 16, 256, 0, stream>>>(h2, Wh1, bh1, Wh2, bh2, out);
}

// Round 4
// 266.742 us; speedup vs baseline: 6.7409x; 1.3966x over previous
//
#include <hip/hip_runtime.h>
#include <hip/hip_bf16.h>
#include <math.h>

#define N_NODES 100000
#define N_EDGES 600000
#define F1 128   // conv1 width
#define F2 64    // conv2 width

typedef __attribute__((ext_vector_type(8))) short bf16x8;
typedef __attribute__((ext_vector_type(4))) float f32x4;

// ---------------- degree / normalization ----------------

__global__ void deg_kernel(const int* __restrict__ dst, int* __restrict__ deg) {
    int e = blockIdx.x * blockDim.x + threadIdx.x;
    if (e < N_EDGES) atomicAdd(&deg[dst[e]], 1);
}

__global__ void dinv_kernel(const int* __restrict__ deg, float* __restrict__ dinv) {
    int n = blockIdx.x * blockDim.x + threadIdx.x;
    if (n < N_NODES) dinv[n] = rsqrtf((float)(deg[n] + 1));  // +1 self-loop
}

// ---------------- region allocation (wave scan + one atomic per wave) ----------------

__global__ void alloc_kernel(const int* __restrict__ deg, int* __restrict__ counter,
                             int* __restrict__ off) {
    int i = blockIdx.x * blockDim.x + threadIdx.x;
    int d = (i < N_NODES) ? deg[i] : 0;
    int incl = d;
    #pragma unroll
    for (int o = 1; o < 64; o <<= 1) {
        int v = __shfl_up(incl, o);
        if ((threadIdx.x & 63) >= o) incl += v;
    }
    int base = 0;
    if ((threadIdx.x & 63) == 63) base = atomicAdd(counter, incl);
    base = __shfl(base, 63);
    if (i < N_NODES) off[i] = base + incl - d;
}

__global__ void copy_kernel(const int* __restrict__ a, int* __restrict__ b, int n) {
    int i = blockIdx.x * blockDim.x + threadIdx.x;
    if (i < n) b[i] = a[i];
}

// ---------------- CSR fill: bucket edges by dst ----------------

__global__ void fill_kernel(const int* __restrict__ src, const int* __restrict__ dst,
                            int* __restrict__ cur, int* __restrict__ csr_src) {
    int e = blockIdx.x * blockDim.x + threadIdx.x;
    if (e < N_EDGES) {
        int d = dst[e];
        int pos = atomicAdd(&cur[d], 1);
        csr_src[pos] = src[e];
    }
}

// ---------------- W convert: Wt[n][k] = bf16(W[k][n]) ----------------

template<int K, int N>
__global__ void convw_kernel(const float* __restrict__ W, unsigned short* __restrict__ Wt) {
    int i = blockIdx.x * blockDim.x + threadIdx.x;
    if (i < K * N) {
        int k = i / N, n = i % N;
        __hip_bfloat16 h = __float2bfloat16(W[i]);
        Wt[n * K + k] = *reinterpret_cast<unsigned short*>(&h);
    }
}

// ---------------- MFMA GEMM: out[N,HO] = X[N,128] @ W[128,HO], bf16 inputs, f32 accum ----
// 256 threads = 4 waves; each wave does 16 rows x HO cols. No LDS, no barriers.
// A: 16x16x32 layout A[m=l&15][k=(l>>4)*8+j]; B from Wt[n][k] (transposed bf16).

__device__ inline short bfbits(float x) {
    __hip_bfloat16 h = __float2bfloat16(x);
    return *reinterpret_cast<short*>(&h);
}

template<int HO>
__global__ __launch_bounds__(256) void mgemm_kernel(const float* __restrict__ X,
                                                    const unsigned short* __restrict__ Wt,
                                                    float* __restrict__ out) {
    constexpr int NT = HO / 16;
    const int tid = threadIdx.x;
    const int wid = tid >> 6;
    const int l   = tid & 63;
    const int l16 = l & 15;
    const int kg  = l >> 4;          // 0..3 (k-group of 8)

    const int row = blockIdx.x * 64 + wid * 16 + l16;
    const int rowc = (row < N_NODES) ? row : (N_NODES - 1);

    // A fragments for 4 k-steps of 32
    bf16x8 a[4];
    const float* xp = X + (size_t)rowc * 128 + kg * 8;
    #pragma unroll
    for (int ks = 0; ks < 4; ks++) {
        const float4 v0 = *(const float4*)(xp + ks * 32);
        const float4 v1 = *(const float4*)(xp + ks * 32 + 4);
        bf16x8 t;
        t[0] = bfbits(v0.x); t[1] = bfbits(v0.y); t[2] = bfbits(v0.z); t[3] = bfbits(v0.w);
        t[4] = bfbits(v1.x); t[5] = bfbits(v1.y); t[6] = bfbits(v1.z); t[7] = bfbits(v1.w);
        a[ks] = t;
    }

    f32x4 acc[NT];
    #pragma unroll
    for (int t = 0; t < NT; t++) acc[t] = (f32x4){0.f, 0.f, 0.f, 0.f};

    #pragma unroll
    for (int t = 0; t < NT; t++) {
        const unsigned short* wp = Wt + (size_t)(t * 16 + l16) * 128 + kg * 8;
        #pragma unroll
        for (int ks = 0; ks < 4; ks++) {
            bf16x8 b = *(const bf16x8*)(wp + ks * 32);
            acc[t] = __builtin_amdgcn_mfma_f32_16x16x32_bf16(a[ks], b, acc[t], 0, 0, 0);
        }
    }

    // D layout: col = l&15, row = (l>>4)*4 + reg
    const int orow0 = blockIdx.x * 64 + wid * 16 + kg * 4;
    #pragma unroll
    for (int t = 0; t < NT; t++) {
        #pragma unroll
        for (int r = 0; r < 4; r++) {
            const int orow = orow0 + r;
            if (orow < N_NODES) out[(size_t)orow * HO + t * 16 + l16] = acc[t][r];
        }
    }
}

// ---------------- fused aggregation: h[n] = relu(sum xw[s]*norm + xw[n]*dinv^2 + b) -------

template<int F>
__global__ __launch_bounds__(256) void gather_kernel(const float* __restrict__ xw,
                                                     const float* __restrict__ dinv,
                                                     const int* __restrict__ off,
                                                     const int* __restrict__ deg,
                                                     const int* __restrict__ csr_src,
                                                     const float* __restrict__ bias,
                                                     float* __restrict__ h) {
    constexpr int LANES = F / 4;        // float4 lanes per node: 32 or 16
    constexpr int NPB = 256 / LANES;    // nodes per block
    const int n = blockIdx.x * NPB + threadIdx.x / LANES;
    if (n >= N_NODES) return;
    const int c = threadIdx.x % LANES;

    const float dn = dinv[n];
    float4 acc = ((const float4*)xw)[(size_t)n * LANES + c];
    const float sl = dn * dn;           // self-loop norm
    acc.x *= sl; acc.y *= sl; acc.z *= sl; acc.w *= sl;

    const int e0 = off[n];
    const int e1 = e0 + deg[n];
    for (int j = e0; j < e1; j++) {
        const int s = csr_src[j];
        const float nr = dinv[s] * dn;
        const float4 v = ((const float4*)xw)[(size_t)s * LANES + c];
        acc.x += v.x * nr; acc.y += v.y * nr; acc.z += v.z * nr; acc.w += v.w * nr;
    }
    const float4 bv = *(const float4*)&bias[c * 4];
    acc.x = fmaxf(acc.x + bv.x, 0.f);
    acc.y = fmaxf(acc.y + bv.y, 0.f);
    acc.z = fmaxf(acc.z + bv.z, 0.f);
    acc.w = fmaxf(acc.w + bv.w, 0.f);
    ((float4*)h)[(size_t)n * LANES + c] = acc;
}

// ---------------- head: gelu(h2 @ Wh1 + bh1) @ Wh2 + bh2 -> sigmoid ----------------

__global__ __launch_bounds__(256) void head_kernel(const float* __restrict__ h2,
                                                   const float* __restrict__ Wh1,
                                                   const float* __restrict__ bh1,
                                                   const float* __restrict__ Wh2,
                                                   const float* __restrict__ bh2,
                                                   float* __restrict__ out) {
    __shared__ float W1s[64 * 16];
    __shared__ float h2s[16 * 64];
    __shared__ float W2s[16];
    __shared__ float b1s[16];
    const int tid = threadIdx.x;
    const int node0 = blockIdx.x * 16;

    ((float4*)W1s)[tid] = ((const float4*)Wh1)[tid];
    if (tid < 16) { W2s[tid] = Wh2[tid]; b1s[tid] = bh1[tid]; }
    {
        int node = node0 + tid / 16;
        ((float4*)h2s)[tid] = (node < N_NODES)
            ? ((const float4*)h2)[(size_t)node * 16 + (tid % 16)]
            : make_float4(0.f, 0.f, 0.f, 0.f);
    }
    __syncthreads();

    const int l  = tid & 15;
    const int nl = tid >> 4;
    const int node = node0 + nl;

    float s = b1s[l];
    #pragma unroll 8
    for (int k = 0; k < 64; k++)
        s += h2s[nl * 64 + k] * W1s[k * 16 + l];
    float g = 0.5f * s * (1.f + erff(s * 0.70710678118654752f));
    float p = g * W2s[l];
    p += __shfl_xor(p, 1);
    p += __shfl_xor(p, 2);
    p += __shfl_xor(p, 4);
    p += __shfl_xor(p, 8);
    if (l == 0 && node < N_NODES) {
        float z = p + bh2[0];
        out[node] = 1.f / (1.f + expf(-z));
    }
}

// ---------------- launch ----------------

extern "C" void kernel_launch(void* const* d_in, const int* in_sizes, int n_in,
                              void* d_out, int out_size, void* d_ws, size_t ws_size,
                              hipStream_t stream) {
    const float* x   = (const float*)d_in[0];
    const int*   ei  = (const int*)d_in[1];
    const float* W1  = (const float*)d_in[2];
    const float* b1  = (const float*)d_in[3];
    const float* W2  = (const float*)d_in[4];
    const float* b2  = (const float*)d_in[5];
    const float* Wh1 = (const float*)d_in[6];
    const float* bh1 = (const float*)d_in[7];
    const float* Wh2 = (const float*)d_in[8];
    const float* bh2 = (const float*)d_in[9];
    float* out = (float*)d_out;

    const int* srcA = ei;             // edge_index[0]
    const int* dstA = ei + N_EDGES;   // edge_index[1]

    char* ws = (char*)d_ws;
    const size_t MB = 1u << 20;
    float* dinv    = (float*)(ws);                    // N f32
    int*   deg     = (int*)  (ws + MB / 2);           // N i32 (+1 counter)
    int*   counter = deg + N_NODES;                   // 1 i32
    int*   off     = (int*)  (ws + MB);               // N i32
    int*   cur     = (int*)  (ws + MB + MB / 2);      // N i32
    int*   csr_src = (int*)  (ws + 2 * MB);           // E i32 (2.4MB)
    unsigned short* Wt1 = (unsigned short*)(ws + 4 * MB + MB / 2);   // 128x128 bf16 (32KB)
    unsigned short* Wt2 = Wt1 + 128 * 128;                           // 64x128 bf16 (16KB)
    const size_t szNF = (size_t)N_NODES * F1 * sizeof(float);   // 51.2 MB
    float* bufA = (float*)(ws + 5 * MB);              // xw1; later xw2|h2
    float* bufB = (float*)(ws + 5 * MB + szNF);       // h1
    float* xw2  = bufA;                               // N x 64
    float* h2   = bufA + (size_t)N_NODES * F2;        // N x 64

    // degree + dinv + bucket allocation + CSR fill
    hipMemsetAsync(deg, 0, (N_NODES + 1) * sizeof(int), stream);   // deg + counter
    deg_kernel<<<(N_EDGES + 255) / 256, 256, 0, stream>>>(dstA, deg);
    dinv_kernel<<<(N_NODES + 255) / 256, 256, 0, stream>>>(deg, dinv);
    alloc_kernel<<<(N_NODES + 255) / 256, 256, 0, stream>>>(deg, counter, off);
    copy_kernel<<<(N_NODES + 255) / 256, 256, 0, stream>>>(off, cur, N_NODES);
    fill_kernel<<<(N_EDGES + 255) / 256, 256, 0, stream>>>(srcA, dstA, cur, csr_src);

    // weight conversion (bf16, transposed)
    convw_kernel<128, 128><<<(128 * 128 + 255) / 256, 256, 0, stream>>>(W1, Wt1);
    convw_kernel<128, 64><<<(128 * 64 + 255) / 256, 256, 0, stream>>>(W2, Wt2);

    // layer 1
    mgemm_kernel<128><<<(N_NODES + 63) / 64, 256, 0, stream>>>(x, Wt1, bufA);
    gather_kernel<128><<<(N_NODES * 32 + 255) / 256, 256, 0, stream>>>(bufA, dinv, off, deg, csr_src, b1, bufB);

    // layer 2
    mgemm_kernel<64><<<(N_NODES + 63) / 64, 256, 0, stream>>>(bufB, Wt2, xw2);
    gather_kernel<64><<<(N_NODES * 16 + 255) / 256, 256, 0, stream>>>(xw2, dinv, off, deg, csr_src, b2, h2);

    // head
    head_kernel<<<(N_NODES + 15) / 16, 256, 0, stream>>>(h2, Wh1, bh1, Wh2, bh2, out);
}

// Round 5
// 233.755 us; speedup vs baseline: 7.6922x; 1.1411x over previous
//
#include <hip/hip_runtime.h>
#include <hip/hip_bf16.h>
#include <math.h>

#define N_NODES 100000
#define N_EDGES 600000
#define F1 128   // conv1 width
#define F2 64    // conv2 width

typedef __attribute__((ext_vector_type(8))) short bf16x8;
typedef __attribute__((ext_vector_type(4))) float f32x4;

__device__ inline short bfbits(float x) {
    __hip_bfloat16 h = __float2bfloat16(x);
    return *reinterpret_cast<short*>(&h);
}
__device__ inline float bf2f(short u) {
    unsigned int x = ((unsigned int)(unsigned short)u) << 16;
    return __uint_as_float(x);
}

// ---------------- degree ----------------

__global__ void deg_kernel(const int* __restrict__ dst, int* __restrict__ deg) {
    int e = blockIdx.x * blockDim.x + threadIdx.x;
    if (e < N_EDGES) atomicAdd(&deg[dst[e]], 1);
}

// ---------------- fused: dinv + region alloc (wave scan + one atomic) + cur init ----------

__global__ void prep_kernel(const int* __restrict__ deg, int* __restrict__ counter,
                            float* __restrict__ dinv, int* __restrict__ off,
                            int* __restrict__ cur) {
    int i = blockIdx.x * blockDim.x + threadIdx.x;
    int d = (i < N_NODES) ? deg[i] : 0;
    if (i < N_NODES) dinv[i] = rsqrtf((float)(d + 1));   // +1 self-loop
    int incl = d;
    #pragma unroll
    for (int o = 1; o < 64; o <<= 1) {
        int v = __shfl_up(incl, o);
        if ((threadIdx.x & 63) >= o) incl += v;
    }
    int base = 0;
    if ((threadIdx.x & 63) == 63) base = atomicAdd(counter, incl);
    base = __shfl(base, 63);
    if (i < N_NODES) {
        int o = base + incl - d;
        off[i] = o;
        cur[i] = o;
    }
}

// ---------------- CSR fill: bucket edges by dst ----------------

__global__ void fill_kernel(const int* __restrict__ src, const int* __restrict__ dst,
                            int* __restrict__ cur, int* __restrict__ csr_src) {
    int e = blockIdx.x * blockDim.x + threadIdx.x;
    if (e < N_EDGES) {
        int d = dst[e];
        int pos = atomicAdd(&cur[d], 1);
        csr_src[pos] = src[e];
    }
}

// ---------------- W convert (both layers): Wt[n][k] = bf16(W[k][n]) ----------------

__global__ void convw_kernel(const float* __restrict__ W1, const float* __restrict__ W2,
                             unsigned short* __restrict__ Wt1, unsigned short* __restrict__ Wt2) {
    int i = blockIdx.x * blockDim.x + threadIdx.x;
    if (i < 128 * 128) {
        int k = i / 128, n = i % 128;
        Wt1[n * 128 + k] = (unsigned short)bfbits(W1[i]);
    } else if (i < 128 * 128 + 128 * 64) {
        int j = i - 128 * 128;
        int k = j / 64, n = j % 64;
        Wt2[n * 128 + k] = (unsigned short)bfbits(W2[j]);
    }
}

// ---------------- MFMA GEMM: out[N,HO] = X[N,128] @ Wt^T, bf16 out ----------------
// 256 threads = 4 waves; wave does 16 rows x HO cols. No LDS, no barriers.
// A 16x16x32 layout: A[m=l&15][k=(l>>4)*8+j]. D: col=l&15, row=(l>>4)*4+reg.

template<int HO, bool IN_BF16>
__global__ __launch_bounds__(256) void mgemm_kernel(const void* __restrict__ Xv,
                                                    const unsigned short* __restrict__ Wt,
                                                    unsigned short* __restrict__ out) {
    constexpr int NT = HO / 16;
    const int tid = threadIdx.x;
    const int wid = tid >> 6;
    const int l   = tid & 63;
    const int l16 = l & 15;
    const int kg  = l >> 4;          // 0..3

    const int row = blockIdx.x * 64 + wid * 16 + l16;
    const int rowc = (row < N_NODES) ? row : (N_NODES - 1);

    bf16x8 a[4];
    if (IN_BF16) {
        const unsigned short* xb = (const unsigned short*)Xv + (size_t)rowc * 128 + kg * 8;
        #pragma unroll
        for (int ks = 0; ks < 4; ks++) a[ks] = *(const bf16x8*)(xb + ks * 32);
    } else {
        const float* xp = (const float*)Xv + (size_t)rowc * 128 + kg * 8;
        #pragma unroll
        for (int ks = 0; ks < 4; ks++) {
            const float4 v0 = *(const float4*)(xp + ks * 32);
            const float4 v1 = *(const float4*)(xp + ks * 32 + 4);
            bf16x8 t;
            t[0] = bfbits(v0.x); t[1] = bfbits(v0.y); t[2] = bfbits(v0.z); t[3] = bfbits(v0.w);
            t[4] = bfbits(v1.x); t[5] = bfbits(v1.y); t[6] = bfbits(v1.z); t[7] = bfbits(v1.w);
            a[ks] = t;
        }
    }

    f32x4 acc[NT];
    #pragma unroll
    for (int t = 0; t < NT; t++) acc[t] = (f32x4){0.f, 0.f, 0.f, 0.f};

    #pragma unroll
    for (int t = 0; t < NT; t++) {
        const unsigned short* wp = Wt + (size_t)(t * 16 + l16) * 128 + kg * 8;
        #pragma unroll
        for (int ks = 0; ks < 4; ks++) {
            bf16x8 b = *(const bf16x8*)(wp + ks * 32);
            acc[t] = __builtin_amdgcn_mfma_f32_16x16x32_bf16(a[ks], b, acc[t], 0, 0, 0);
        }
    }

    const int orow0 = blockIdx.x * 64 + wid * 16 + kg * 4;
    #pragma unroll
    for (int t = 0; t < NT; t++) {
        #pragma unroll
        for (int r = 0; r < 4; r++) {
            const int orow = orow0 + r;
            if (orow < N_NODES)
                out[(size_t)orow * HO + t * 16 + l16] = (unsigned short)bfbits(acc[t][r]);
        }
    }
}

// ---------------- fused aggregation (bf16 in/out, f32 accum) ----------------
// h[n] = relu(sum_{s} xw[s]*dinv[s]*dinv[n] + xw[n]*dinv[n]^2 + b)

template<int F>
__global__ __launch_bounds__(256) void gather_kernel(const unsigned short* __restrict__ xw,
                                                     const float* __restrict__ dinv,
                                                     const int* __restrict__ off,
                                                     const int* __restrict__ deg,
                                                     const int* __restrict__ csr_src,
                                                     const float* __restrict__ bias,
                                                     unsigned short* __restrict__ h) {
    constexpr int LANES = F / 8;        // bf16x8 lanes per node: 16 or 8
    constexpr int NPB = 256 / LANES;    // nodes per block
    const int n = blockIdx.x * NPB + threadIdx.x / LANES;
    if (n >= N_NODES) return;
    const int c = threadIdx.x % LANES;

    const float dn = dinv[n];
    float acc[8];
    {
        const bf16x8 v = *(const bf16x8*)(xw + (size_t)n * F + c * 8);
        const float sl = dn * dn;
        #pragma unroll
        for (int i = 0; i < 8; i++) acc[i] = bf2f(v[i]) * sl;
    }

    const int e0 = off[n];
    const int e1 = e0 + deg[n];
    for (int j = e0; j < e1; j++) {
        const int s = csr_src[j];
        const float nr = dinv[s] * dn;
        const bf16x8 v = *(const bf16x8*)(xw + (size_t)s * F + c * 8);
        #pragma unroll
        for (int i = 0; i < 8; i++) acc[i] += bf2f(v[i]) * nr;
    }

    bf16x8 o;
    #pragma unroll
    for (int i = 0; i < 8; i++) {
        float b = bias[c * 8 + i];
        o[i] = bfbits(fmaxf(acc[i] + b, 0.f));
    }
    *(bf16x8*)(h + (size_t)n * F + c * 8) = o;
}

// ---------------- head: gelu(h2 @ Wh1 + bh1) @ Wh2 + bh2 -> sigmoid ----------------

__global__ __launch_bounds__(256) void head_kernel(const unsigned short* __restrict__ h2,
                                                   const float* __restrict__ Wh1,
                                                   const float* __restrict__ bh1,
                                                   const float* __restrict__ Wh2,
                                                   const float* __restrict__ bh2,
                                                   float* __restrict__ out) {
    __shared__ float W1s[64 * 16];
    __shared__ float h2s[16 * 64];
    __shared__ float W2s[16];
    __shared__ float b1s[16];
    const int tid = threadIdx.x;
    const int node0 = blockIdx.x * 16;

    ((float4*)W1s)[tid] = ((const float4*)Wh1)[tid];
    if (tid < 16) { W2s[tid] = Wh2[tid]; b1s[tid] = bh1[tid]; }
    if (tid < 128) {                       // 16 nodes x 8 bf16x8-chunks
        int node = node0 + tid / 8;
        int ch = tid % 8;
        if (node < N_NODES) {
            bf16x8 v = *(const bf16x8*)(h2 + (size_t)node * 64 + ch * 8);
            #pragma unroll
            for (int i = 0; i < 8; i++) h2s[(tid / 8) * 64 + ch * 8 + i] = bf2f(v[i]);
        } else {
            #pragma unroll
            for (int i = 0; i < 8; i++) h2s[(tid / 8) * 64 + ch * 8 + i] = 0.f;
        }
    }
    __syncthreads();

    const int l  = tid & 15;
    const int nl = tid >> 4;
    const int node = node0 + nl;

    float s = b1s[l];
    #pragma unroll 8
    for (int k = 0; k < 64; k++)
        s += h2s[nl * 64 + k] * W1s[k * 16 + l];
    float g = 0.5f * s * (1.f + erff(s * 0.70710678118654752f));
    float p = g * W2s[l];
    p += __shfl_xor(p, 1);
    p += __shfl_xor(p, 2);
    p += __shfl_xor(p, 4);
    p += __shfl_xor(p, 8);
    if (l == 0 && node < N_NODES) {
        float z = p + bh2[0];
        out[node] = 1.f / (1.f + expf(-z));
    }
}

// ---------------- launch ----------------

extern "C" void kernel_launch(void* const* d_in, const int* in_sizes, int n_in,
                              void* d_out, int out_size, void* d_ws, size_t ws_size,
                              hipStream_t stream) {
    const float* x   = (const float*)d_in[0];
    const int*   ei  = (const int*)d_in[1];
    const float* W1  = (const float*)d_in[2];
    const float* b1  = (const float*)d_in[3];
    const float* W2  = (const float*)d_in[4];
    const float* b2  = (const float*)d_in[5];
    const float* Wh1 = (const float*)d_in[6];
    const float* bh1 = (const float*)d_in[7];
    const float* Wh2 = (const float*)d_in[8];
    const float* bh2 = (const float*)d_in[9];
    float* out = (float*)d_out;

    const int* srcA = ei;             // edge_index[0]
    const int* dstA = ei + N_EDGES;   // edge_index[1]

    char* ws = (char*)d_ws;
    const size_t MB = 1u << 20;
    float* dinv    = (float*)(ws);                    // N f32
    int*   deg     = (int*)  (ws + MB / 2);           // N i32 (+1 counter)
    int*   counter = deg + N_NODES;                   // 1 i32
    int*   off     = (int*)  (ws + MB);               // N i32
    int*   cur     = (int*)  (ws + MB + MB / 2);      // N i32
    int*   csr_src = (int*)  (ws + 2 * MB);           // E i32 (2.4MB)
    unsigned short* Wt1 = (unsigned short*)(ws + 4 * MB + MB / 2);   // 128x128 bf16
    unsigned short* Wt2 = Wt1 + 128 * 128;                           // 64x128 bf16
    unsigned short* bufA = (unsigned short*)(ws + 5 * MB);           // xw1 (N x 128 bf16, 25.6MB)
    unsigned short* bufB = (unsigned short*)(ws + 32 * MB);          // h1  (N x 128 bf16)
    unsigned short* xw2  = bufA;                                     // N x 64 bf16
    unsigned short* h2   = bufA + (size_t)N_NODES * F2;              // N x 64 bf16

    // degree + (dinv, off, cur) + CSR fill + weight conversion
    hipMemsetAsync(deg, 0, (N_NODES + 1) * sizeof(int), stream);   // deg + counter
    deg_kernel<<<(N_EDGES + 255) / 256, 256, 0, stream>>>(dstA, deg);
    prep_kernel<<<(N_NODES + 255) / 256, 256, 0, stream>>>(deg, counter, dinv, off, cur);
    fill_kernel<<<(N_EDGES + 255) / 256, 256, 0, stream>>>(srcA, dstA, cur, csr_src);
    convw_kernel<<<(128 * 128 + 128 * 64 + 255) / 256, 256, 0, stream>>>(W1, W2, Wt1, Wt2);

    // layer 1
    mgemm_kernel<128, false><<<(N_NODES + 63) / 64, 256, 0, stream>>>(x, Wt1, bufA);
    gather_kernel<128><<<(N_NODES * 16 + 255) / 256, 256, 0, stream>>>(bufA, dinv, off, deg, csr_src, b1, bufB);

    // layer 2
    mgemm_kernel<64, true><<<(N_NODES + 63) / 64, 256, 0, stream>>>(bufB, Wt2, xw2);
    gather_kernel<64><<<(N_NODES * 8 + 255) / 256, 256, 0, stream>>>(xw2, dinv, off, deg, csr_src, b2, h2);

    // head
    head_kernel<<<(N_NODES + 15) / 16, 256, 0, stream>>>(h2, Wh1, bh1, Wh2, bh2, out);
}

// Round 6
// 228.879 us; speedup vs baseline: 7.8561x; 1.0213x over previous
//
#include <hip/hip_runtime.h>
#include <hip/hip_bf16.h>
#include <math.h>

#define N_NODES 100000
#define N_EDGES 600000
#define F1 128   // conv1 width
#define F2 64    // conv2 width

typedef __attribute__((ext_vector_type(8))) short bf16x8;
typedef __attribute__((ext_vector_type(4))) float f32x4;

__device__ inline short bfbits(float x) {
    __hip_bfloat16 h = __float2bfloat16(x);
    return *reinterpret_cast<short*>(&h);
}
__device__ inline float bf2f(short u) {
    unsigned int x = ((unsigned int)(unsigned short)u) << 16;
    return __uint_as_float(x);
}

// ---------------- degree ----------------

__global__ void deg_kernel(const int* __restrict__ dst, int* __restrict__ deg) {
    int e = blockIdx.x * blockDim.x + threadIdx.x;
    if (e < N_EDGES) atomicAdd(&deg[dst[e]], 1);
}

// ---------------- fused: dinv + region alloc (wave scan + one atomic) + cur init ----------

__global__ void prep_kernel(const int* __restrict__ deg, int* __restrict__ counter,
                            float* __restrict__ dinv, int* __restrict__ off,
                            int* __restrict__ cur) {
    int i = blockIdx.x * blockDim.x + threadIdx.x;
    int d = (i < N_NODES) ? deg[i] : 0;
    if (i < N_NODES) dinv[i] = rsqrtf((float)(d + 1));   // +1 self-loop
    int incl = d;
    #pragma unroll
    for (int o = 1; o < 64; o <<= 1) {
        int v = __shfl_up(incl, o);
        if ((threadIdx.x & 63) >= o) incl += v;
    }
    int base = 0;
    if ((threadIdx.x & 63) == 63) base = atomicAdd(counter, incl);
    base = __shfl(base, 63);
    if (i < N_NODES) {
        int o = base + incl - d;
        off[i] = o;
        cur[i] = o;
    }
}

// ---------------- CSR fill: bucket edges by dst ----------------

__global__ void fill_kernel(const int* __restrict__ src, const int* __restrict__ dst,
                            int* __restrict__ cur, int* __restrict__ csr_src) {
    int e = blockIdx.x * blockDim.x + threadIdx.x;
    if (e < N_EDGES) {
        int d = dst[e];
        int pos = atomicAdd(&cur[d], 1);
        csr_src[pos] = src[e];
    }
}

// ---------------- W convert (both layers): Wt[n][k] = bf16(W[k][n]) ----------------

__global__ void convw_kernel(const float* __restrict__ W1, const float* __restrict__ W2,
                             unsigned short* __restrict__ Wt1, unsigned short* __restrict__ Wt2) {
    int i = blockIdx.x * blockDim.x + threadIdx.x;
    if (i < 128 * 128) {
        int k = i / 128, n = i % 128;
        Wt1[n * 128 + k] = (unsigned short)bfbits(W1[i]);
    } else if (i < 128 * 128 + 128 * 64) {
        int j = i - 128 * 128;
        int k = j / 64, n = j % 64;
        Wt2[n * 128 + k] = (unsigned short)bfbits(W2[j]);
    }
}

// ---------------- MFMA GEMM: out[N,HO] = X[N,128] @ Wt^T, bf16 out ----------------
// 256 threads = 4 waves; wave does 16 rows x HO cols. No LDS, no barriers.
// A 16x16x32 layout: A[m=l&15][k=(l>>4)*8+j]. D: col=l&15, row=(l>>4)*4+reg.

template<int HO, bool IN_BF16>
__global__ __launch_bounds__(256) void mgemm_kernel(const void* __restrict__ Xv,
                                                    const unsigned short* __restrict__ Wt,
                                                    unsigned short* __restrict__ out) {
    constexpr int NT = HO / 16;
    const int tid = threadIdx.x;
    const int wid = tid >> 6;
    const int l   = tid & 63;
    const int l16 = l & 15;
    const int kg  = l >> 4;          // 0..3

    const int row = blockIdx.x * 64 + wid * 16 + l16;
    const int rowc = (row < N_NODES) ? row : (N_NODES - 1);

    bf16x8 a[4];
    if (IN_BF16) {
        const unsigned short* xb = (const unsigned short*)Xv + (size_t)rowc * 128 + kg * 8;
        #pragma unroll
        for (int ks = 0; ks < 4; ks++) a[ks] = *(const bf16x8*)(xb + ks * 32);
    } else {
        const float* xp = (const float*)Xv + (size_t)rowc * 128 + kg * 8;
        #pragma unroll
        for (int ks = 0; ks < 4; ks++) {
            const float4 v0 = *(const float4*)(xp + ks * 32);
            const float4 v1 = *(const float4*)(xp + ks * 32 + 4);
            bf16x8 t;
            t[0] = bfbits(v0.x); t[1] = bfbits(v0.y); t[2] = bfbits(v0.z); t[3] = bfbits(v0.w);
            t[4] = bfbits(v1.x); t[5] = bfbits(v1.y); t[6] = bfbits(v1.z); t[7] = bfbits(v1.w);
            a[ks] = t;
        }
    }

    f32x4 acc[NT];
    #pragma unroll
    for (int t = 0; t < NT; t++) acc[t] = (f32x4){0.f, 0.f, 0.f, 0.f};

    #pragma unroll
    for (int t = 0; t < NT; t++) {
        const unsigned short* wp = Wt + (size_t)(t * 16 + l16) * 128 + kg * 8;
        #pragma unroll
        for (int ks = 0; ks < 4; ks++) {
            bf16x8 b = *(const bf16x8*)(wp + ks * 32);
            acc[t] = __builtin_amdgcn_mfma_f32_16x16x32_bf16(a[ks], b, acc[t], 0, 0, 0);
        }
    }

    const int orow0 = blockIdx.x * 64 + wid * 16 + kg * 4;
    #pragma unroll
    for (int t = 0; t < NT; t++) {
        #pragma unroll
        for (int r = 0; r < 4; r++) {
            const int orow = orow0 + r;
            if (orow < N_NODES)
                out[(size_t)orow * HO + t * 16 + l16] = (unsigned short)bfbits(acc[t][r]);
        }
    }
}

// ---------------- fused aggregation (bf16 in, f32 accum), batch-4 edge pipeline ----------
// h[n] = relu(sum_{s} xw[s]*dinv[s]*dinv[n] + xw[n]*dinv[n]^2 + b)
// HEAD=true additionally computes: sigmoid(gelu(h @ Wh1 + bh1) @ Wh2 + bh2) -> out[n]

template<int F, bool HEAD>
__global__ __launch_bounds__(256) void gather_kernel(const unsigned short* __restrict__ xw,
                                                     const float* __restrict__ dinv,
                                                     const int* __restrict__ off,
                                                     const int* __restrict__ deg,
                                                     const int* __restrict__ csr_src,
                                                     const float* __restrict__ bias,
                                                     unsigned short* __restrict__ h,
                                                     const float* __restrict__ Wh1,
                                                     const float* __restrict__ bh1,
                                                     const float* __restrict__ Wh2,
                                                     const float* __restrict__ bh2,
                                                     float* __restrict__ out) {
    constexpr int LANES = F / 8;        // bf16x8 lanes per node: 16 or 8
    constexpr int NPB = 256 / LANES;    // nodes per block
    __shared__ float W1s[HEAD ? 64 * 16 : 1];
    __shared__ float b1s[HEAD ? 16 : 1];
    __shared__ float W2s[HEAD ? 16 : 1];
    if constexpr (HEAD) {
        ((float4*)W1s)[threadIdx.x] = ((const float4*)Wh1)[threadIdx.x];  // 1024 floats
        if (threadIdx.x < 16) { b1s[threadIdx.x] = bh1[threadIdx.x]; W2s[threadIdx.x] = Wh2[threadIdx.x]; }
        __syncthreads();
    }

    const int n = blockIdx.x * NPB + threadIdx.x / LANES;
    if (n >= N_NODES) return;
    const int c = threadIdx.x % LANES;

    const float dn = dinv[n];
    float acc[8];
    {
        const bf16x8 v = *(const bf16x8*)(xw + (size_t)n * F + c * 8);
        const float sl = dn * dn;
        #pragma unroll
        for (int i = 0; i < 8; i++) acc[i] = bf2f(v[i]) * sl;
    }

    const int e0 = off[n];
    const int e1 = e0 + deg[n];
    for (int j = e0; j < e1; j += 4) {
        float w[4]; bf16x8 v[4];
        #pragma unroll
        for (int u = 0; u < 4; u++) {
            const int jj = j + u;
            const int jc = (jj < e1) ? jj : (e1 - 1);
            const int s = csr_src[jc];
            w[u] = (jj < e1) ? dinv[s] * dn : 0.f;
            v[u] = *(const bf16x8*)(xw + (size_t)s * F + c * 8);
        }
        #pragma unroll
        for (int u = 0; u < 4; u++) {
            #pragma unroll
            for (int i = 0; i < 8; i++) acc[i] += bf2f(v[u][i]) * w[u];
        }
    }

    #pragma unroll
    for (int i = 0; i < 8; i++) acc[i] = fmaxf(acc[i] + bias[c * 8 + i], 0.f);

    if constexpr (!HEAD) {
        bf16x8 o;
        #pragma unroll
        for (int i = 0; i < 8; i++) o[i] = bfbits(acc[i]);
        *(bf16x8*)(h + (size_t)n * F + c * 8) = o;
    } else {
        // acc = h2 row features [c*8, c*8+8). Head: 16 hidden units.
        float p[16];
        #pragma unroll
        for (int u = 0; u < 16; u++) p[u] = 0.f;
        #pragma unroll
        for (int i = 0; i < 8; i++) {
            const float hv = acc[i];
            const float* wr = &W1s[(c * 8 + i) * 16];
            const float4 wa = *(const float4*)(wr + 0);
            const float4 wb = *(const float4*)(wr + 4);
            const float4 wc = *(const float4*)(wr + 8);
            const float4 wd = *(const float4*)(wr + 12);
            p[0]  += hv * wa.x; p[1]  += hv * wa.y; p[2]  += hv * wa.z; p[3]  += hv * wa.w;
            p[4]  += hv * wb.x; p[5]  += hv * wb.y; p[6]  += hv * wb.z; p[7]  += hv * wb.w;
            p[8]  += hv * wc.x; p[9]  += hv * wc.y; p[10] += hv * wc.z; p[11] += hv * wc.w;
            p[12] += hv * wd.x; p[13] += hv * wd.y; p[14] += hv * wd.z; p[15] += hv * wd.w;
        }
        // reduce across the 8 lanes of this node's group (lanes are 8-aligned)
        #pragma unroll
        for (int o = 1; o < 8; o <<= 1) {
            #pragma unroll
            for (int u = 0; u < 16; u++) p[u] += __shfl_xor(p[u], o);
        }
        // each lane handles 2 hidden units: gelu + dot with Wh2
        float z = 0.f;
        #pragma unroll
        for (int t = 0; t < 2; t++) {
            const int u = c * 2 + t;
            const float s = p[u] + b1s[u];
            const float g = 0.5f * s * (1.f + erff(s * 0.70710678118654752f));
            z += g * W2s[u];
        }
        z += __shfl_xor(z, 1);
        z += __shfl_xor(z, 2);
        z += __shfl_xor(z, 4);
        if (c == 0) {
            const float zz = z + bh2[0];
            out[n] = 1.f / (1.f + expf(-zz));
        }
    }
}

// ---------------- launch ----------------

extern "C" void kernel_launch(void* const* d_in, const int* in_sizes, int n_in,
                              void* d_out, int out_size, void* d_ws, size_t ws_size,
                              hipStream_t stream) {
    const float* x   = (const float*)d_in[0];
    const int*   ei  = (const int*)d_in[1];
    const float* W1  = (const float*)d_in[2];
    const float* b1  = (const float*)d_in[3];
    const float* W2  = (const float*)d_in[4];
    const float* b2  = (const float*)d_in[5];
    const float* Wh1 = (const float*)d_in[6];
    const float* bh1 = (const float*)d_in[7];
    const float* Wh2 = (const float*)d_in[8];
    const float* bh2 = (const float*)d_in[9];
    float* out = (float*)d_out;

    const int* srcA = ei;             // edge_index[0]
    const int* dstA = ei + N_EDGES;   // edge_index[1]

    char* ws = (char*)d_ws;
    const size_t MB = 1u << 20;
    float* dinv    = (float*)(ws);                    // N f32
    int*   deg     = (int*)  (ws + MB / 2);           // N i32 (+1 counter)
    int*   counter = deg + N_NODES;                   // 1 i32
    int*   off     = (int*)  (ws + MB);               // N i32
    int*   cur     = (int*)  (ws + MB + MB / 2);      // N i32
    int*   csr_src = (int*)  (ws + 2 * MB);           // E i32 (2.4MB)
    unsigned short* Wt1 = (unsigned short*)(ws + 4 * MB + MB / 2);   // 128x128 bf16
    unsigned short* Wt2 = Wt1 + 128 * 128;                           // 64x128 bf16
    unsigned short* bufA = (unsigned short*)(ws + 5 * MB);           // xw1 (N x 128 bf16, 25.6MB)
    unsigned short* bufB = (unsigned short*)(ws + 32 * MB);          // h1  (N x 128 bf16)
    unsigned short* xw2  = bufA;                                     // N x 64 bf16

    // degree + (dinv, off, cur) + CSR fill + weight conversion
    hipMemsetAsync(deg, 0, (N_NODES + 1) * sizeof(int), stream);   // deg + counter
    deg_kernel<<<(N_EDGES + 255) / 256, 256, 0, stream>>>(dstA, deg);
    prep_kernel<<<(N_NODES + 255) / 256, 256, 0, stream>>>(deg, counter, dinv, off, cur);
    fill_kernel<<<(N_EDGES + 255) / 256, 256, 0, stream>>>(srcA, dstA, cur, csr_src);
    convw_kernel<<<(128 * 128 + 128 * 64 + 255) / 256, 256, 0, stream>>>(W1, W2, Wt1, Wt2);

    // layer 1
    mgemm_kernel<128, false><<<(N_NODES + 63) / 64, 256, 0, stream>>>(x, Wt1, bufA);
    gather_kernel<128, false><<<(N_NODES * 16 + 255) / 256, 256, 0, stream>>>(
        bufA, dinv, off, deg, csr_src, b1, bufB, nullptr, nullptr, nullptr, nullptr, nullptr);

    // layer 2 + fused head
    mgemm_kernel<64, true><<<(N_NODES + 63) / 64, 256, 0, stream>>>(bufB, Wt2, xw2);
    gather_kernel<64, true><<<(N_NODES * 8 + 255) / 256, 256, 0, stream>>>(
        xw2, dinv, off, deg, csr_src, b2, nullptr, Wh1, bh1, Wh2, bh2, out);
}

// Round 7
// 219.999 us; speedup vs baseline: 8.1732x; 1.0404x over previous
//
#include <hip/hip_runtime.h>
#include <hip/hip_bf16.h>
#include <math.h>

#define N_NODES 100000
#define N_EDGES 600000
#define F1 128   // conv1 width
#define F2 64    // conv2 width

typedef __attribute__((ext_vector_type(8))) short bf16x8;
typedef __attribute__((ext_vector_type(4))) float f32x4;

__device__ inline short bfbits(float x) {
    __hip_bfloat16 h = __float2bfloat16(x);
    return *reinterpret_cast<short*>(&h);
}
__device__ inline float bf2f(short u) {
    unsigned int x = ((unsigned int)(unsigned short)u) << 16;
    return __uint_as_float(x);
}

// ---------------- degree ----------------

__global__ void deg_kernel(const int* __restrict__ dst, int* __restrict__ deg) {
    int e = blockIdx.x * blockDim.x + threadIdx.x;
    if (e < N_EDGES) atomicAdd(&deg[dst[e]], 1);
}

// ---------------- fused: dinv + region alloc (wave scan + one atomic) + cur init ----------

__global__ void prep_kernel(const int* __restrict__ deg, int* __restrict__ counter,
                            float* __restrict__ dinv, int* __restrict__ off,
                            int* __restrict__ cur) {
    int i = blockIdx.x * blockDim.x + threadIdx.x;
    int d = (i < N_NODES) ? deg[i] : 0;
    if (i < N_NODES) dinv[i] = rsqrtf((float)(d + 1));   // +1 self-loop
    int incl = d;
    #pragma unroll
    for (int o = 1; o < 64; o <<= 1) {
        int v = __shfl_up(incl, o);
        if ((threadIdx.x & 63) >= o) incl += v;
    }
    int base = 0;
    if ((threadIdx.x & 63) == 63) base = atomicAdd(counter, incl);
    base = __shfl(base, 63);
    if (i < N_NODES) {
        int o = base + incl - d;
        off[i] = o;
        cur[i] = o;
    }
}

// ---------------- CSR fill: bucket edges by dst, store (src, norm) packed ----------------

__global__ void fill_kernel(const int* __restrict__ src, const int* __restrict__ dst,
                            const float* __restrict__ dinv,
                            int* __restrict__ cur, int2* __restrict__ csr) {
    int e = blockIdx.x * blockDim.x + threadIdx.x;
    if (e < N_EDGES) {
        int s = src[e], d = dst[e];
        float w = dinv[s] * dinv[d];
        int pos = atomicAdd(&cur[d], 1);
        csr[pos] = make_int2(s, __float_as_int(w));
    }
}

// ---------------- W convert (both layers): Wt[n][k] = bf16(W[k][n]) ----------------

__global__ void convw_kernel(const float* __restrict__ W1, const float* __restrict__ W2,
                             unsigned short* __restrict__ Wt1, unsigned short* __restrict__ Wt2) {
    int i = blockIdx.x * blockDim.x + threadIdx.x;
    if (i < 128 * 128) {
        int k = i / 128, n = i % 128;
        Wt1[n * 128 + k] = (unsigned short)bfbits(W1[i]);
    } else if (i < 128 * 128 + 128 * 64) {
        int j = i - 128 * 128;
        int k = j / 64, n = j % 64;
        Wt2[n * 128 + k] = (unsigned short)bfbits(W2[j]);
    }
}

// ---------------- MFMA GEMM: out[N,HO] = X[N,128] @ Wt^T, bf16 out ----------------
// 256 threads = 4 waves; wave does 16 rows x HO cols. No LDS, no barriers.

template<int HO, bool IN_BF16>
__global__ __launch_bounds__(256) void mgemm_kernel(const void* __restrict__ Xv,
                                                    const unsigned short* __restrict__ Wt,
                                                    unsigned short* __restrict__ out) {
    constexpr int NT = HO / 16;
    const int tid = threadIdx.x;
    const int wid = tid >> 6;
    const int l   = tid & 63;
    const int l16 = l & 15;
    const int kg  = l >> 4;          // 0..3

    const int row = blockIdx.x * 64 + wid * 16 + l16;
    const int rowc = (row < N_NODES) ? row : (N_NODES - 1);

    bf16x8 a[4];
    if (IN_BF16) {
        const unsigned short* xb = (const unsigned short*)Xv + (size_t)rowc * 128 + kg * 8;
        #pragma unroll
        for (int ks = 0; ks < 4; ks++) a[ks] = *(const bf16x8*)(xb + ks * 32);
    } else {
        const float* xp = (const float*)Xv + (size_t)rowc * 128 + kg * 8;
        #pragma unroll
        for (int ks = 0; ks < 4; ks++) {
            const float4 v0 = *(const float4*)(xp + ks * 32);
            const float4 v1 = *(const float4*)(xp + ks * 32 + 4);
            bf16x8 t;
            t[0] = bfbits(v0.x); t[1] = bfbits(v0.y); t[2] = bfbits(v0.z); t[3] = bfbits(v0.w);
            t[4] = bfbits(v1.x); t[5] = bfbits(v1.y); t[6] = bfbits(v1.z); t[7] = bfbits(v1.w);
            a[ks] = t;
        }
    }

    f32x4 acc[NT];
    #pragma unroll
    for (int t = 0; t < NT; t++) acc[t] = (f32x4){0.f, 0.f, 0.f, 0.f};

    #pragma unroll
    for (int t = 0; t < NT; t++) {
        const unsigned short* wp = Wt + (size_t)(t * 16 + l16) * 128 + kg * 8;
        #pragma unroll
        for (int ks = 0; ks < 4; ks++) {
            bf16x8 b = *(const bf16x8*)(wp + ks * 32);
            acc[t] = __builtin_amdgcn_mfma_f32_16x16x32_bf16(a[ks], b, acc[t], 0, 0, 0);
        }
    }

    const int orow0 = blockIdx.x * 64 + wid * 16 + kg * 4;
    #pragma unroll
    for (int t = 0; t < NT; t++) {
        #pragma unroll
        for (int r = 0; r < 4; r++) {
            const int orow = orow0 + r;
            if (orow < N_NODES)
                out[(size_t)orow * HO + t * 16 + l16] = (unsigned short)bfbits(acc[t][r]);
        }
    }
}

// ---------------- fused aggregation (bf16 in/out, f32 accum), batch-4, 2-deep chain ------
// h[n] = relu(sum_{(s,w) in csr[n]} xw[s]*w + xw[n]*dinv[n]^2 + b)

template<int F>
__global__ __launch_bounds__(256) void gather_kernel(const unsigned short* __restrict__ xw,
                                                     const float* __restrict__ dinv,
                                                     const int* __restrict__ off,
                                                     const int* __restrict__ deg,
                                                     const int2* __restrict__ csr,
                                                     const float* __restrict__ bias,
                                                     unsigned short* __restrict__ h) {
    constexpr int LANES = F / 8;        // bf16x8 lanes per node: 16 or 8
    constexpr int NPB = 256 / LANES;    // nodes per block
    const int n = blockIdx.x * NPB + threadIdx.x / LANES;
    if (n >= N_NODES) return;
    const int c = threadIdx.x % LANES;

    const float dn = dinv[n];
    float acc[8];
    {
        const bf16x8 v = *(const bf16x8*)(xw + (size_t)n * F + c * 8);
        const float sl = dn * dn;
        #pragma unroll
        for (int i = 0; i < 8; i++) acc[i] = bf2f(v[i]) * sl;
    }

    const int e0 = off[n];
    const int e1 = e0 + deg[n];
    for (int j = e0; j < e1; j += 4) {
        float w[4]; bf16x8 v[4];
        #pragma unroll
        for (int u = 0; u < 4; u++) {
            const int jj = j + u;
            const int jc = (jj < e1) ? jj : (e1 - 1);
            const int2 ee = csr[jc];
            w[u] = (jj < e1) ? __int_as_float(ee.y) : 0.f;
            v[u] = *(const bf16x8*)(xw + (size_t)ee.x * F + c * 8);
        }
        #pragma unroll
        for (int u = 0; u < 4; u++) {
            #pragma unroll
            for (int i = 0; i < 8; i++) acc[i] += bf2f(v[u][i]) * w[u];
        }
    }

    bf16x8 o;
    #pragma unroll
    for (int i = 0; i < 8; i++) o[i] = bfbits(fmaxf(acc[i] + bias[c * 8 + i], 0.f));
    *(bf16x8*)(h + (size_t)n * F + c * 8) = o;
}

// ---------------- head: gelu(h2 @ Wh1 + bh1) @ Wh2 + bh2 -> sigmoid ----------------

__global__ __launch_bounds__(256) void head_kernel(const unsigned short* __restrict__ h2,
                                                   const float* __restrict__ Wh1,
                                                   const float* __restrict__ bh1,
                                                   const float* __restrict__ Wh2,
                                                   const float* __restrict__ bh2,
                                                   float* __restrict__ out) {
    __shared__ float W1s[64 * 16];
    __shared__ float h2s[16 * 64];
    __shared__ float W2s[16];
    __shared__ float b1s[16];
    const int tid = threadIdx.x;
    const int node0 = blockIdx.x * 16;

    ((float4*)W1s)[tid] = ((const float4*)Wh1)[tid];
    if (tid < 16) { W2s[tid] = Wh2[tid]; b1s[tid] = bh1[tid]; }
    if (tid < 128) {                       // 16 nodes x 8 bf16x8-chunks
        int node = node0 + tid / 8;
        int ch = tid % 8;
        if (node < N_NODES) {
            bf16x8 v = *(const bf16x8*)(h2 + (size_t)node * 64 + ch * 8);
            #pragma unroll
            for (int i = 0; i < 8; i++) h2s[(tid / 8) * 64 + ch * 8 + i] = bf2f(v[i]);
        } else {
            #pragma unroll
            for (int i = 0; i < 8; i++) h2s[(tid / 8) * 64 + ch * 8 + i] = 0.f;
        }
    }
    __syncthreads();

    const int l  = tid & 15;
    const int nl = tid >> 4;
    const int node = node0 + nl;

    float s = b1s[l];
    #pragma unroll 8
    for (int k = 0; k < 64; k++)
        s += h2s[nl * 64 + k] * W1s[k * 16 + l];
    float g = 0.5f * s * (1.f + erff(s * 0.70710678118654752f));
    float p = g * W2s[l];
    p += __shfl_xor(p, 1);
    p += __shfl_xor(p, 2);
    p += __shfl_xor(p, 4);
    p += __shfl_xor(p, 8);
    if (l == 0 && node < N_NODES) {
        float z = p + bh2[0];
        out[node] = 1.f / (1.f + expf(-z));
    }
}

// ---------------- launch ----------------

extern "C" void kernel_launch(void* const* d_in, const int* in_sizes, int n_in,
                              void* d_out, int out_size, void* d_ws, size_t ws_size,
                              hipStream_t stream) {
    const float* x   = (const float*)d_in[0];
    const int*   ei  = (const int*)d_in[1];
    const float* W1  = (const float*)d_in[2];
    const float* b1  = (const float*)d_in[3];
    const float* W2  = (const float*)d_in[4];
    const float* b2  = (const float*)d_in[5];
    const float* Wh1 = (const float*)d_in[6];
    const float* bh1 = (const float*)d_in[7];
    const float* Wh2 = (const float*)d_in[8];
    const float* bh2 = (const float*)d_in[9];
    float* out = (float*)d_out;

    const int* srcA = ei;             // edge_index[0]
    const int* dstA = ei + N_EDGES;   // edge_index[1]

    char* ws = (char*)d_ws;
    const size_t MB = 1u << 20;
    float* dinv    = (float*)(ws);                    // N f32
    int*   deg     = (int*)  (ws + MB / 2);           // N i32 (+1 counter)
    int*   counter = deg + N_NODES;                   // 1 i32
    int*   off     = (int*)  (ws + MB);               // N i32
    int*   cur     = (int*)  (ws + MB + MB / 2);      // N i32
    int2*  csr     = (int2*) (ws + 2 * MB);           // E int2 (4.8MB)
    unsigned short* Wt1 = (unsigned short*)(ws + 7 * MB);            // 128x128 bf16
    unsigned short* Wt2 = Wt1 + 128 * 128;                           // 64x128 bf16
    unsigned short* bufA = (unsigned short*)(ws + 8 * MB);           // xw1 (N x 128 bf16, 25.6MB)
    unsigned short* bufB = (unsigned short*)(ws + 34 * MB);          // h1  (N x 128 bf16)
    unsigned short* xw2  = bufA;                                     // N x 64 bf16
    unsigned short* h2   = bufA + (size_t)N_NODES * F2;              // N x 64 bf16

    // degree + (dinv, off, cur) + CSR fill + weight conversion
    hipMemsetAsync(deg, 0, (N_NODES + 1) * sizeof(int), stream);   // deg + counter
    deg_kernel<<<(N_EDGES + 255) / 256, 256, 0, stream>>>(dstA, deg);
    prep_kernel<<<(N_NODES + 255) / 256, 256, 0, stream>>>(deg, counter, dinv, off, cur);
    fill_kernel<<<(N_EDGES + 255) / 256, 256, 0, stream>>>(srcA, dstA, dinv, cur, csr);
    convw_kernel<<<(128 * 128 + 128 * 64 + 255) / 256, 256, 0, stream>>>(W1, W2, Wt1, Wt2);

    // layer 1
    mgemm_kernel<128, false><<<(N_NODES + 63) / 64, 256, 0, stream>>>(x, Wt1, bufA);
    gather_kernel<128><<<(N_NODES * 16 + 255) / 256, 256, 0, stream>>>(bufA, dinv, off, deg, csr, b1, bufB);

    // layer 2
    mgemm_kernel<64, true><<<(N_NODES + 63) / 64, 256, 0, stream>>>(bufB, Wt2, xw2);
    gather_kernel<64><<<(N_NODES * 8 + 255) / 256, 256, 0, stream>>>(xw2, dinv, off, deg, csr, b2, h2);

    // head
    head_kernel<<<(N_NODES + 15) / 16, 256, 0, stream>>>(h2, Wh1, bh1, Wh2, bh2, out);
}

// Round 8
// 211.266 us; speedup vs baseline: 8.5111x; 1.0413x over previous
//
#include <hip/hip_runtime.h>
#include <hip/hip_bf16.h>
#include <math.h>

#define N_NODES 100000
#define N_EDGES 600000
#define F1 128   // conv1 width
#define F2 64    // conv2 width

#define DEG_BLOCKS   ((N_EDGES + 255) / 256)           // 2344
#define CONVW_ELEMS  (128 * 128 + 128 * 64)
#define CONVW_BLOCKS ((CONVW_ELEMS + 255) / 256)       // 96
#define MG1_BLOCKS   ((N_NODES + 63) / 64)             // 1563

typedef __attribute__((ext_vector_type(8))) short bf16x8;
typedef __attribute__((ext_vector_type(4))) float f32x4;

__device__ inline short bfbits(float x) {
    __hip_bfloat16 h = __float2bfloat16(x);
    return *reinterpret_cast<short*>(&h);
}
__device__ inline float bf2f(short u) {
    unsigned int x = ((unsigned int)(unsigned short)u) << 16;
    return __uint_as_float(x);
}

// ---------------- fused: degree count || weight conversion ----------------

__global__ __launch_bounds__(256) void dc_kernel(const int* __restrict__ dst, int* __restrict__ deg,
                                                 const float* __restrict__ W1, const float* __restrict__ W2,
                                                 unsigned short* __restrict__ Wt1, unsigned short* __restrict__ Wt2) {
    if (blockIdx.x < DEG_BLOCKS) {
        int e = blockIdx.x * 256 + threadIdx.x;
        if (e < N_EDGES) atomicAdd(&deg[dst[e]], 1);
    } else {
        int i = (blockIdx.x - DEG_BLOCKS) * 256 + threadIdx.x;
        if (i < 128 * 128) {
            int k = i / 128, n = i % 128;
            Wt1[n * 128 + k] = (unsigned short)bfbits(W1[i]);
        } else if (i < CONVW_ELEMS) {
            int j = i - 128 * 128;
            int k = j / 64, n = j % 64;
            Wt2[n * 128 + k] = (unsigned short)bfbits(W2[j]);
        }
    }
}

// ---------------- fused: dinv + region alloc (wave scan + one atomic) + cur init ----------

__global__ void prep_kernel(const int* __restrict__ deg, int* __restrict__ counter,
                            float* __restrict__ dinv, int* __restrict__ off,
                            int* __restrict__ cur) {
    int i = blockIdx.x * blockDim.x + threadIdx.x;
    int d = (i < N_NODES) ? deg[i] : 0;
    if (i < N_NODES) dinv[i] = rsqrtf((float)(d + 1));   // +1 self-loop
    int incl = d;
    #pragma unroll
    for (int o = 1; o < 64; o <<= 1) {
        int v = __shfl_up(incl, o);
        if ((threadIdx.x & 63) >= o) incl += v;
    }
    int base = 0;
    if ((threadIdx.x & 63) == 63) base = atomicAdd(counter, incl);
    base = __shfl(base, 63);
    if (i < N_NODES) {
        int o = base + incl - d;
        off[i] = o;
        cur[i] = o;
    }
}

// ---------------- fused: MFMA GEMM layer-1 || CSR fill ----------------
// blocks [0, MG1_BLOCKS): out[N,128] = bf16(X[N,128] fp32) @ Wt1^T  (4 waves, 16 rows each)
// blocks [MG1_BLOCKS, +DEG_BLOCKS): bucket edges by dst, store (src, norm)

__global__ __launch_bounds__(256) void mf_kernel(const float* __restrict__ X,
                                                 const unsigned short* __restrict__ Wt,
                                                 unsigned short* __restrict__ out,
                                                 const int* __restrict__ src, const int* __restrict__ dst,
                                                 const float* __restrict__ dinv,
                                                 int* __restrict__ cur, int2* __restrict__ csr) {
    const int tid = threadIdx.x;
    if (blockIdx.x >= MG1_BLOCKS) {
        int e = (blockIdx.x - MG1_BLOCKS) * 256 + tid;
        if (e < N_EDGES) {
            int s = src[e], d = dst[e];
            float w = dinv[s] * dinv[d];
            int pos = atomicAdd(&cur[d], 1);
            csr[pos] = make_int2(s, __float_as_int(w));
        }
        return;
    }

    constexpr int NT = 128 / 16;
    const int wid = tid >> 6;
    const int l   = tid & 63;
    const int l16 = l & 15;
    const int kg  = l >> 4;          // 0..3

    const int row = blockIdx.x * 64 + wid * 16 + l16;
    const int rowc = (row < N_NODES) ? row : (N_NODES - 1);

    bf16x8 a[4];
    const float* xp = X + (size_t)rowc * 128 + kg * 8;
    #pragma unroll
    for (int ks = 0; ks < 4; ks++) {
        const float4 v0 = *(const float4*)(xp + ks * 32);
        const float4 v1 = *(const float4*)(xp + ks * 32 + 4);
        bf16x8 t;
        t[0] = bfbits(v0.x); t[1] = bfbits(v0.y); t[2] = bfbits(v0.z); t[3] = bfbits(v0.w);
        t[4] = bfbits(v1.x); t[5] = bfbits(v1.y); t[6] = bfbits(v1.z); t[7] = bfbits(v1.w);
        a[ks] = t;
    }

    f32x4 acc[NT];
    #pragma unroll
    for (int t = 0; t < NT; t++) acc[t] = (f32x4){0.f, 0.f, 0.f, 0.f};

    #pragma unroll
    for (int t = 0; t < NT; t++) {
        const unsigned short* wp = Wt + (size_t)(t * 16 + l16) * 128 + kg * 8;
        #pragma unroll
        for (int ks = 0; ks < 4; ks++) {
            bf16x8 b = *(const bf16x8*)(wp + ks * 32);
            acc[t] = __builtin_amdgcn_mfma_f32_16x16x32_bf16(a[ks], b, acc[t], 0, 0, 0);
        }
    }

    const int orow0 = blockIdx.x * 64 + wid * 16 + kg * 4;
    #pragma unroll
    for (int t = 0; t < NT; t++) {
        #pragma unroll
        for (int r = 0; r < 4; r++) {
            const int orow = orow0 + r;
            if (orow < N_NODES)
                out[(size_t)orow * 128 + t * 16 + l16] = (unsigned short)bfbits(acc[t][r]);
        }
    }
}

// ---------------- MFMA GEMM (layer 2, bf16 in): out[N,64] ----------------

__global__ __launch_bounds__(256) void mgemm2_kernel(const unsigned short* __restrict__ Xb,
                                                     const unsigned short* __restrict__ Wt,
                                                     unsigned short* __restrict__ out) {
    constexpr int NT = 64 / 16;
    const int tid = threadIdx.x;
    const int wid = tid >> 6;
    const int l   = tid & 63;
    const int l16 = l & 15;
    const int kg  = l >> 4;

    const int row = blockIdx.x * 64 + wid * 16 + l16;
    const int rowc = (row < N_NODES) ? row : (N_NODES - 1);

    bf16x8 a[4];
    const unsigned short* xb = Xb + (size_t)rowc * 128 + kg * 8;
    #pragma unroll
    for (int ks = 0; ks < 4; ks++) a[ks] = *(const bf16x8*)(xb + ks * 32);

    f32x4 acc[NT];
    #pragma unroll
    for (int t = 0; t < NT; t++) acc[t] = (f32x4){0.f, 0.f, 0.f, 0.f};

    #pragma unroll
    for (int t = 0; t < NT; t++) {
        const unsigned short* wp = Wt + (size_t)(t * 16 + l16) * 128 + kg * 8;
        #pragma unroll
        for (int ks = 0; ks < 4; ks++) {
            bf16x8 b = *(const bf16x8*)(wp + ks * 32);
            acc[t] = __builtin_amdgcn_mfma_f32_16x16x32_bf16(a[ks], b, acc[t], 0, 0, 0);
        }
    }

    const int orow0 = blockIdx.x * 64 + wid * 16 + kg * 4;
    #pragma unroll
    for (int t = 0; t < NT; t++) {
        #pragma unroll
        for (int r = 0; r < 4; r++) {
            const int orow = orow0 + r;
            if (orow < N_NODES)
                out[(size_t)orow * 64 + t * 16 + l16] = (unsigned short)bfbits(acc[t][r]);
        }
    }
}

// ---------------- fused aggregation (bf16 in/out, f32 accum), batch-4, 2-deep chain ------

template<int F>
__global__ __launch_bounds__(256) void gather_kernel(const unsigned short* __restrict__ xw,
                                                     const float* __restrict__ dinv,
                                                     const int* __restrict__ off,
                                                     const int* __restrict__ deg,
                                                     const int2* __restrict__ csr,
                                                     const float* __restrict__ bias,
                                                     unsigned short* __restrict__ h) {
    constexpr int LANES = F / 8;        // bf16x8 lanes per node: 16 or 8
    constexpr int NPB = 256 / LANES;
    const int n = blockIdx.x * NPB + threadIdx.x / LANES;
    if (n >= N_NODES) return;
    const int c = threadIdx.x % LANES;

    const float dn = dinv[n];
    float acc[8];
    {
        const bf16x8 v = *(const bf16x8*)(xw + (size_t)n * F + c * 8);
        const float sl = dn * dn;
        #pragma unroll
        for (int i = 0; i < 8; i++) acc[i] = bf2f(v[i]) * sl;
    }

    const int e0 = off[n];
    const int e1 = e0 + deg[n];
    for (int j = e0; j < e1; j += 4) {
        float w[4]; bf16x8 v[4];
        #pragma unroll
        for (int u = 0; u < 4; u++) {
            const int jj = j + u;
            const int jc = (jj < e1) ? jj : (e1 - 1);
            const int2 ee = csr[jc];
            w[u] = (jj < e1) ? __int_as_float(ee.y) : 0.f;
            v[u] = *(const bf16x8*)(xw + (size_t)ee.x * F + c * 8);
        }
        #pragma unroll
        for (int u = 0; u < 4; u++) {
            #pragma unroll
            for (int i = 0; i < 8; i++) acc[i] += bf2f(v[u][i]) * w[u];
        }
    }

    bf16x8 o;
    #pragma unroll
    for (int i = 0; i < 8; i++) o[i] = bfbits(fmaxf(acc[i] + bias[c * 8 + i], 0.f));
    *(bf16x8*)(h + (size_t)n * F + c * 8) = o;
}

// ---------------- head: gelu(h2 @ Wh1 + bh1) @ Wh2 + bh2 -> sigmoid ----------------

__global__ __launch_bounds__(256) void head_kernel(const unsigned short* __restrict__ h2,
                                                   const float* __restrict__ Wh1,
                                                   const float* __restrict__ bh1,
                                                   const float* __restrict__ Wh2,
                                                   const float* __restrict__ bh2,
                                                   float* __restrict__ out) {
    __shared__ float W1s[64 * 16];
    __shared__ float h2s[16 * 64];
    __shared__ float W2s[16];
    __shared__ float b1s[16];
    const int tid = threadIdx.x;
    const int node0 = blockIdx.x * 16;

    ((float4*)W1s)[tid] = ((const float4*)Wh1)[tid];
    if (tid < 16) { W2s[tid] = Wh2[tid]; b1s[tid] = bh1[tid]; }
    if (tid < 128) {                       // 16 nodes x 8 bf16x8-chunks
        int node = node0 + tid / 8;
        int ch = tid % 8;
        if (node < N_NODES) {
            bf16x8 v = *(const bf16x8*)(h2 + (size_t)node * 64 + ch * 8);
            #pragma unroll
            for (int i = 0; i < 8; i++) h2s[(tid / 8) * 64 + ch * 8 + i] = bf2f(v[i]);
        } else {
            #pragma unroll
            for (int i = 0; i < 8; i++) h2s[(tid / 8) * 64 + ch * 8 + i] = 0.f;
        }
    }
    __syncthreads();

    const int l  = tid & 15;
    const int nl = tid >> 4;
    const int node = node0 + nl;

    float s = b1s[l];
    #pragma unroll 8
    for (int k = 0; k < 64; k++)
        s += h2s[nl * 64 + k] * W1s[k * 16 + l];
    float g = 0.5f * s * (1.f + erff(s * 0.70710678118654752f));
    float p = g * W2s[l];
    p += __shfl_xor(p, 1);
    p += __shfl_xor(p, 2);
    p += __shfl_xor(p, 4);
    p += __shfl_xor(p, 8);
    if (l == 0 && node < N_NODES) {
        float z = p + bh2[0];
        out[node] = 1.f / (1.f + expf(-z));
    }
}

// ---------------- launch ----------------

extern "C" void kernel_launch(void* const* d_in, const int* in_sizes, int n_in,
                              void* d_out, int out_size, void* d_ws, size_t ws_size,
                              hipStream_t stream) {
    const float* x   = (const float*)d_in[0];
    const int*   ei  = (const int*)d_in[1];
    const float* W1  = (const float*)d_in[2];
    const float* b1  = (const float*)d_in[3];
    const float* W2  = (const float*)d_in[4];
    const float* b2  = (const float*)d_in[5];
    const float* Wh1 = (const float*)d_in[6];
    const float* bh1 = (const float*)d_in[7];
    const float* Wh2 = (const float*)d_in[8];
    const float* bh2 = (const float*)d_in[9];
    float* out = (float*)d_out;

    const int* srcA = ei;             // edge_index[0]
    const int* dstA = ei + N_EDGES;   // edge_index[1]

    char* ws = (char*)d_ws;
    const size_t MB = 1u << 20;
    float* dinv    = (float*)(ws);                    // N f32
    int*   deg     = (int*)  (ws + MB / 2);           // N i32 (+1 counter)
    int*   counter = deg + N_NODES;                   // 1 i32
    int*   off     = (int*)  (ws + MB);               // N i32
    int*   cur     = (int*)  (ws + MB + MB / 2);      // N i32
    int2*  csr     = (int2*) (ws + 2 * MB);           // E int2 (4.8MB)
    unsigned short* Wt1 = (unsigned short*)(ws + 7 * MB);            // 128x128 bf16
    unsigned short* Wt2 = Wt1 + 128 * 128;                           // 64x128 bf16
    unsigned short* bufA = (unsigned short*)(ws + 8 * MB);           // xw1 (N x 128 bf16, 25.6MB)
    unsigned short* bufB = (unsigned short*)(ws + 34 * MB);          // h1  (N x 128 bf16)
    unsigned short* xw2  = bufA;                                     // N x 64 bf16
    unsigned short* h2   = bufA + (size_t)N_NODES * F2;              // N x 64 bf16

    // zero deg+counter; then (deg || convw); prep; (mgemm1 || fill)
    hipMemsetAsync(deg, 0, (N_NODES + 1) * sizeof(int), stream);
    dc_kernel<<<DEG_BLOCKS + CONVW_BLOCKS, 256, 0, stream>>>(dstA, deg, W1, W2, Wt1, Wt2);
    prep_kernel<<<(N_NODES + 255) / 256, 256, 0, stream>>>(deg, counter, dinv, off, cur);
    mf_kernel<<<MG1_BLOCKS + DEG_BLOCKS, 256, 0, stream>>>(x, Wt1, bufA, srcA, dstA, dinv, cur, csr);

    // layer 1 aggregation
    gather_kernel<128><<<(N_NODES * 16 + 255) / 256, 256, 0, stream>>>(bufA, dinv, off, deg, csr, b1, bufB);

    // layer 2
    mgemm2_kernel<<<(N_NODES + 63) / 64, 256, 0, stream>>>(bufB, Wt2, xw2);
    gather_kernel<64><<<(N_NODES * 8 + 255) / 256, 256, 0, stream>>>(xw2, dinv, off, deg, csr, b2, h2);

    // head
    head_kernel<<<(N_NODES + 15) / 16, 256, 0, stream>>>(h2, Wh1, bh1, Wh2, bh2, out);
}